// Round 7
// baseline (411.001 us; speedup 1.0000x reference)
//
#include <hip/hip_runtime.h>
#include <math.h>

#define B_ 64
#define M_ 1024
#define H_ 64
#define N_ (B_*M_)   // 65536

typedef _Float16 half8 __attribute__((ext_vector_type(8)));
typedef float  floatx4 __attribute__((ext_vector_type(4)));

#define MFMA16(a,b,c) __builtin_amdgcn_mfma_f32_16x16x32_f16(a,b,c,0,0,0)
#define MED3(a,b,c)   __builtin_amdgcn_fmed3f(a,b,c)

// ---------------- encoder: h = relu(relu(x@w1+b1)@w2+b2) (+ f16 split + sq) ------
__global__ __launch_bounds__(256) void enc_kernel(
    const float* __restrict__ x,     // [N,4]
    const float* __restrict__ w1,    // [4,32]
    const float* __restrict__ b1,    // [32]
    const float* __restrict__ w2,    // [32,64]
    const float* __restrict__ b2,    // [64]
    float* __restrict__ h,           // [N,64]
    _Float16* __restrict__ hhi,      // [N,64]
    _Float16* __restrict__ hlo,      // [N,64]
    float* __restrict__ sq)          // [N]
{
    __shared__ float sw1[4*32];
    __shared__ float sb1[32];
    __shared__ float sw2[32*64];
    __shared__ float sb2[64];
    int t = threadIdx.x;
    for (int i = t; i < 128; i += 256) sw1[i] = w1[i];
    if (t < 32) sb1[t] = b1[t];
    for (int i = t; i < 2048; i += 256) sw2[i] = w2[i];
    if (t < 64) sb2[t] = b2[t];
    __syncthreads();
    int n = blockIdx.x * 256 + t;
    float4 xv = *(const float4*)(x + (size_t)n*4);
    float hid[32];
    #pragma unroll
    for (int o = 0; o < 32; ++o) {
        float a = sb1[o] + xv.x*sw1[0*32+o] + xv.y*sw1[1*32+o]
                        + xv.z*sw1[2*32+o] + xv.w*sw1[3*32+o];
        hid[o] = fmaxf(a, 0.f);
    }
    float* hout = h + (size_t)n*64;
    float sqa = 0.f;
    #pragma unroll 4
    for (int oc = 0; oc < 16; ++oc) {
        float4 acc = make_float4(sb2[oc*4+0], sb2[oc*4+1], sb2[oc*4+2], sb2[oc*4+3]);
        #pragma unroll
        for (int f = 0; f < 32; ++f) {
            float4 w = *(const float4*)(sw2 + f*64 + oc*4);
            float hv = hid[f];
            acc.x += hv*w.x; acc.y += hv*w.y; acc.z += hv*w.z; acc.w += hv*w.w;
        }
        acc.x = fmaxf(acc.x,0.f); acc.y = fmaxf(acc.y,0.f);
        acc.z = fmaxf(acc.z,0.f); acc.w = fmaxf(acc.w,0.f);
        *(float4*)(hout + oc*4) = acc;
        sqa += acc.x*acc.x + acc.y*acc.y + acc.z*acc.z + acc.w*acc.w;
        union { _Float16 f[4]; uint2 u; } Hh, Hl;
        Hh.f[0]=(_Float16)acc.x; Hh.f[1]=(_Float16)acc.y;
        Hh.f[2]=(_Float16)acc.z; Hh.f[3]=(_Float16)acc.w;
        Hl.f[0]=(_Float16)(acc.x-(float)Hh.f[0]); Hl.f[1]=(_Float16)(acc.y-(float)Hh.f[1]);
        Hl.f[2]=(_Float16)(acc.z-(float)Hh.f[2]); Hl.f[3]=(_Float16)(acc.w-(float)Hh.f[3]);
        *(uint2*)(hhi + (size_t)n*64 + oc*4) = Hh.u;
        *(uint2*)(hlo + (size_t)n*64 + oc*4) = Hl.u;
    }
    sq[n] = sqa;
}

// ---------------- convert: h -> (hhi, hlo, sq)  (after edge layer 1) -------------
__global__ __launch_bounds__(256) void convert_kernel(
    const float* __restrict__ h,
    _Float16* __restrict__ hhi, _Float16* __restrict__ hlo,
    float* __restrict__ sq)
{
    int t = threadIdx.x, lane = t & 63, w = t >> 6;
    int base = blockIdx.x * 64 + w * 16;
    for (int it = 0; it < 16; ++it) {
        int i = base + it;
        float v = h[(size_t)i*64 + lane];
        _Float16 hi = (_Float16)v;
        _Float16 lo = (_Float16)(v - (float)hi);
        hhi[(size_t)i*64 + lane] = hi;
        hlo[(size_t)i*64 + lane] = lo;
        float s = v*v;
        #pragma unroll
        for (int off = 1; off < 64; off <<= 1) s += __shfl_xor(s, off, 64);
        if (lane == 0) sq[i] = s;
    }
}

// ---------------- A = h @ W1b  (W1b = rows 64..127 of w1) ----------------
__global__ __launch_bounds__(256) void gemmA_kernel(
    const float* __restrict__ h,
    const float* __restrict__ w1,   // [128,64]
    float* __restrict__ A)
{
    __shared__ float sw[64*64];
    int t = threadIdx.x;
    for (int idx = t; idx < 4096; idx += 256) sw[idx] = w1[4096 + idx];
    __syncthreads();
    int n = blockIdx.x * 256 + t;
    float4 hv[16];
    const float* src = h + (size_t)n*64;
    #pragma unroll
    for (int c = 0; c < 16; ++c) hv[c] = *(const float4*)(src + c*4);
    float* dst = A + (size_t)n*64;
    #pragma unroll 2
    for (int oc = 0; oc < 16; ++oc) {
        float4 acc = make_float4(0.f,0.f,0.f,0.f);
        #pragma unroll
        for (int f = 0; f < 64; ++f) {
            float xv = ((const float*)hv)[f];
            float4 w = *(const float4*)(sw + f*64 + oc*4);
            acc.x += xv*w.x; acc.y += xv*w.y; acc.z += xv*w.z; acc.w += xv*w.w;
        }
        *(float4*)(dst + oc*4) = acc;
    }
}

// ---------------- kNN v14: 256-thr blocks, in-register bitonic merge -----------
// 4 waves x 16 queries = 64 queries/block, grid 1024 (16 blocks/graph, XCD-
// swizzled). 32-cand tiles double-buffered in LDS (XOR-swizzled), 1 barrier
// per phase (write tile T+1 into the free buffer while computing tile T).
// LDS = 20.25KB -> 6 blocks/CU (launch_bounds(256,6)): 24 waves/CU in six
// independent 4-wave sync domains. Selection runs on the MFMA accumulator;
// the 4 per-gid partial lists of each query are merged IN-REGISTER with two
// bitonic rounds (shfl_xor 16 / 32) -- no LDS merge buffer, no final syncs.
__global__ __launch_bounds__(256, 6) void knn_kernel(
    const _Float16* __restrict__ hhi,
    const _Float16* __restrict__ hlo,
    const float* __restrict__ sqg,
    unsigned short* __restrict__ knn)    // [N,16]
{
    __shared__ __align__(16) _Float16 bufH[2][32*64];   // 2 x 4KB hi tiles
    __shared__ __align__(16) _Float16 bufL[2][32*64];   // 2 x 4KB lo tiles
    __shared__ __align__(16) float sqS[1024];           // 4KB

    int t = threadIdx.x, lane = t & 63, w = t >> 6;     // w in [0,4)
    int bi = blockIdx.x;
    int g  = (bi & 7) | ((bi >> 7) << 3);   // 16 blocks/graph share bi%8 -> same XCD
    int qt = (bi >> 3) & 15;                // which 64-query slice of the graph
    const _Float16* hhig = hhi + (size_t)g*M_*64;
    const _Float16* hlog = hlo + (size_t)g*M_*64;
    const float*    sqb  = sqg + (size_t)g*M_;

    ((float4*)sqS)[t] = ((const float4*)sqb)[t];        // stage sq: 256 x 16B

    int m16 = lane & 15, gid = lane >> 4;
    int crow = gid*4, koct = gid*8;
    int sw = m16 & 7;

    // staging: each thread covers granule (rr, gl) of BOTH hi and lo tiles
    int rr = t >> 3;                        // row 0..31 within tile
    int gl = t & 7;                         // logical 16B granule (linear global read)
    int pp = gl ^ (rr & 7);                 // physical granule (XOR swizzle on write)
    const _Float16* srcH = hhig + rr*64 + gl*8;
    const _Float16* srcL = hlog + rr*64 + gl*8;
    _Float16* dstH = bufH[0] + rr*64 + pp*8;   // buf1 at +2048 (f16 units)
    _Float16* dstL = bufL[0] + rr*64 + pp*8;

    // query fragments (B operand): wave w owns queries qt*64 + w*16 + [0,16)
    int qbase = qt*64 + w*16;
    half8 Qh0, Qh1, Ql0, Ql1;
    {
        const _Float16* ph = hhig + (size_t)(qbase + m16)*64;
        const _Float16* pl = hlog + (size_t)(qbase + m16)*64;
        Qh0 = *(const half8*)(ph + koct);
        Qh1 = *(const half8*)(ph + 32 + koct);
        Ql0 = *(const half8*)(pl + koct);
        Ql1 = *(const half8*)(pl + 32 + koct);
    }

    float bd[16];
    #pragma unroll
    for (int k = 0; k < 16; ++k) bd[k] = INFINITY;

    int ts_self = qt*4 + w;     // global 16-cand subtile holding this wave's selves

    // prologue: stage tile 0 directly into buf0
    {
        float4 h0 = *(const float4*)srcH;
        float4 l0 = *(const float4*)srcL;
        *(float4*)dstH = h0;
        *(float4*)dstL = l0;
    }
    __syncthreads();                        // buf0 + sqS ready

    float c1 = 1.f + sqS[qbase + m16];

    int o0 = m16*64 + ((gid ^ sw) * 8);     // swizzled frag offsets (ks0)
    int o1 = o0 ^ 32;                       // ks1 granule ^= 4

    auto insert4 = [&](floatx4 acc, float4 sqv, unsigned cid, bool st) {
        #pragma unroll
        for (int r = 0; r < 4; ++r) {
            float s  = fmaf(-2.f, acc[r], (&sqv.x)[r]);   // sq_j - 2 dot
            float t2 = c1 + s;                            // 1 + d^2  (>0)
            unsigned kb = (__float_as_uint(t2) & 0xFFFFFC00u) | (cid + r);
            float fk = __uint_as_float(kb);
            if (st && (crow + r) == m16) fk = INFINITY;   // self
            float nb0 = fminf(bd[0], fk);
            #pragma unroll
            for (int k = 15; k >= 1; --k) bd[k] = MED3(fk, bd[k-1], bd[k]);
            bd[0] = nb0;
        }
    };

    auto compute = [&](int T, const _Float16* bh, const _Float16* bl) {
        #pragma unroll
        for (int s = 0; s < 2; ++s) {
            int ob = s*1024;
            half8 Ah0 = *(const half8*)(bh + ob + o0);
            half8 Ah1 = *(const half8*)(bh + ob + o1);
            half8 Al0 = *(const half8*)(bl + ob + o0);
            half8 Al1 = *(const half8*)(bl + ob + o1);
            float4 sqv = *(const float4*)(sqS + T*32 + s*16 + crow);
            unsigned cid = (unsigned)(T*32 + s*16 + crow);
            bool st = (T*2 + s) == ts_self;
            floatx4 acc = {0.f, 0.f, 0.f, 0.f};
            acc = MFMA16(Ah0, Qh0, acc);
            acc = MFMA16(Ah1, Qh1, acc);
            acc = MFMA16(Ah0, Ql0, acc);
            acc = MFMA16(Ah1, Ql1, acc);
            acc = MFMA16(Al0, Qh0, acc);
            acc = MFMA16(Al1, Qh1, acc);
            insert4(acc, sqv, cid, st);
        }
    };

    // main loop: 32 tiles of 32 cands; 1 barrier per phase.
    // Phase T: issue global loads of tile T+1, compute tile T from buf[T&1]
    // (hides load latency), vm-wait, ds_write into buf[(T&1)^1] (free since
    // the barrier at end of phase T-1), drain, barrier.
    #pragma unroll 1
    for (int T = 0; T < 32; ++T) {
        size_t o = (size_t)((T+1) & 31) * 2048;
        float4 h1 = *(const float4*)(srcH + o);
        float4 l1 = *(const float4*)(srcL + o);
        const _Float16* bh = (T & 1) ? bufH[1] : bufH[0];
        const _Float16* bl = (T & 1) ? bufL[1] : bufL[0];
        compute(T, bh, bl);
        int sel = ((T & 1) ^ 1) * 2048;
        *(float4*)(dstH + sel) = h1;        // compiler inserts vmcnt before write
        *(float4*)(dstL + sel) = l1;
        asm volatile("s_waitcnt lgkmcnt(0)" ::: "memory");
        __builtin_amdgcn_s_barrier();       // phase boundary
    }

    // ---- in-register merge: 4 per-gid lists -> final top-16 per query ----
    // bd is ascending-sorted. Lanes 16g+m16 (g=0..3) hold partials of query
    // w*16+m16. Two bitonic rounds (xor 16, xor 32): after each, every lane
    // holds the merged lowest-16, sorted ascending.
    #pragma unroll
    for (int rnd = 0; rnd < 2; ++rnd) {
        float rv[16], m[16];
        #pragma unroll
        for (int k = 0; k < 16; ++k) rv[k] = __shfl_xor(bd[k], 16 << rnd, 64);
        #pragma unroll
        for (int k = 0; k < 16; ++k) m[k] = fminf(bd[k], rv[15-k]);
        #pragma unroll
        for (int s = 8; s >= 1; s >>= 1) {
            #pragma unroll
            for (int i = 0; i < 16; ++i) {
                if ((i & s) == 0) {
                    float lo = fminf(m[i], m[i+s]);
                    float hi = fmaxf(m[i], m[i+s]);
                    m[i] = lo; m[i+s] = hi;
                }
            }
        }
        #pragma unroll
        for (int k = 0; k < 16; ++k) bd[k] = m[k];
    }
    if (gid == 0) {
        union { unsigned short us[16]; uint4 v4[2]; } o;
        #pragma unroll
        for (int k = 0; k < 16; ++k)
            o.us[k] = (unsigned short)(__float_as_uint(bd[k]) & 1023u);
        size_t gq = (size_t)g*M_ + qt*64 + w*16 + m16;
        uint4* dst = (uint4*)(knn + gq*16);
        dst[0] = o.v4[0];
        dst[1] = o.v4[1];
    }
}

// ---------------- EdgeConv v3 (MFMA): Cs aliased onto w2f, XCD swizzle ----------
__global__ __launch_bounds__(256) void edge_kernel(
    const float* __restrict__ h,     // [N,64] (in-place out OK: own rows read first)
    const float* __restrict__ A,     // [N,64]
    const unsigned short* __restrict__ knn, // [N,16] local idx
    const float* __restrict__ w1,    // [128,64]
    const float* __restrict__ b1,    // [64]
    const float* __restrict__ w2,    // [64,64]
    const float* __restrict__ b2,    // [64]
    float* __restrict__ hout)
{
    __shared__ __align__(16) _Float16 wdf[16*64*8];   // Wd B-frags (16 KB)
    __shared__ __align__(16) _Float16 w2f[16*64*8];   // W2 B-frags (16 KB) -> Cs after
    float* CsB = (float*)w2f;                          // Cs[4][16][64] alias (16 KB)
    int t = threadIdx.x;
    for (int u = t; u < 512; u += 256) {
        int ulane = u & 63, nt = u >> 7, ks = (u >> 6) & 1;
        int n = nt*16 + (ulane & 15);
        int kbase = ks*32 + ((ulane >> 4) * 8);
        int fh = (((nt*2+ks)*2+0)*64 + ulane)*8;
        int fl = (((nt*2+ks)*2+1)*64 + ulane)*8;
        #pragma unroll
        for (int j = 0; j < 8; ++j) {
            int k = kbase + j;
            float vd = w1[k*64+n] - w1[4096 + k*64+n];
            _Float16 dh = (_Float16)vd;
            wdf[fh+j] = dh;
            wdf[fl+j] = (_Float16)(vd - (float)dh);
            float v2 = w2[k*64+n];
            _Float16 h2 = (_Float16)v2;
            w2f[fh+j] = h2;
            w2f[fl+j] = (_Float16)(v2 - (float)h2);
        }
    }
    __syncthreads();
    int lane = t & 63, wid = t >> 6;
    int m16 = lane & 15, gid = lane >> 4;
    int koct = gid*8, crow = gid*4;
    int bi = blockIdx.x;
    int g  = (bi & 7) | ((bi >> 7) << 3);    // XCD swizzle: graph's blocks share an XCD
    int qt = (bi >> 3) & 15;
    int i0 = g*M_ + qt*64 + wid*16;          // first node of this wave
    const float* Ab = A + (size_t)g*M_*H_;

    half8 W2r[4][2][2];
    #pragma unroll
    for (int nt = 0; nt < 4; ++nt)
        #pragma unroll
        for (int ks = 0; ks < 2; ++ks)
            #pragma unroll
            for (int p = 0; p < 2; ++p)
                W2r[nt][ks][p] = *(const half8*)&w2f[(((nt*2+ks)*2+p)*64+lane)*8];

    float b1v[4];
    #pragma unroll
    for (int nt = 0; nt < 4; ++nt) b1v[nt] = b1[nt*16+m16];
    float b2v = b2[gid*16+m16];
    __syncthreads();   // all waves done reading w2f -> safe to overwrite with Cs

    // ---- Phase 1: C tile = h(16 nodes) @ Wd + b1 -> CsB (over w2f) ----
    half8 Hh[2], Hl[2];
    #pragma unroll
    for (int ks = 0; ks < 2; ++ks) {
        const float* hp = h + (size_t)(i0+m16)*64 + ks*32 + koct;
        float4 v0 = *(const float4*)hp;
        float4 v1 = *(const float4*)(hp+4);
        float va[8] = {v0.x,v0.y,v0.z,v0.w,v1.x,v1.y,v1.z,v1.w};
        #pragma unroll
        for (int j = 0; j < 8; ++j) {
            _Float16 hi = (_Float16)va[j];
            Hh[ks][j] = hi;
            Hl[ks][j] = (_Float16)(va[j]-(float)hi);
        }
    }
    #pragma unroll
    for (int nt = 0; nt < 4; ++nt) {
        floatx4 acc = {b1v[nt], b1v[nt], b1v[nt], b1v[nt]};
        #pragma unroll
        for (int ks = 0; ks < 2; ++ks) {
            half8 wh = *(const half8*)&wdf[(((nt*2+ks)*2+0)*64+lane)*8];
            half8 wl = *(const half8*)&wdf[(((nt*2+ks)*2+1)*64+lane)*8];
            acc = MFMA16(Hh[ks], wh, acc);
            acc = MFMA16(Hh[ks], wl, acc);
            acc = MFMA16(Hl[ks], wh, acc);
        }
        #pragma unroll
        for (int r = 0; r < 4; ++r)
            CsB[((wid*16) + crow + r)*64 + nt*16 + m16] = acc[r];
    }
    __syncthreads();

    // ---- Phase 2: per node, msg = relu(C + A_j), out = max_e msg@W2 + b2 ----
    const unsigned short* knb = knn + (size_t)i0*16;
    #pragma unroll 2
    for (int nn = 0; nn < 16; ++nn) {
        int j = knb[nn*16 + m16];
        const float* Ap = Ab + (size_t)j*64;
        half8 Mh[2], Ml[2];
        #pragma unroll
        for (int ks = 0; ks < 2; ++ks) {
            float4 a0 = *(const float4*)(Ap + ks*32 + koct);
            float4 a1 = *(const float4*)(Ap + ks*32 + koct + 4);
            const float* cp = &CsB[(wid*16 + nn)*64 + ks*32 + koct];
            float4 c0 = *(const float4*)cp;
            float4 c1 = *(const float4*)(cp+4);
            float mv[8] = {
                fmaxf(a0.x+c0.x,0.f), fmaxf(a0.y+c0.y,0.f),
                fmaxf(a0.z+c0.z,0.f), fmaxf(a0.w+c0.w,0.f),
                fmaxf(a1.x+c1.x,0.f), fmaxf(a1.y+c1.y,0.f),
                fmaxf(a1.z+c1.z,0.f), fmaxf(a1.w+c1.w,0.f)};
            #pragma unroll
            for (int jj = 0; jj < 8; ++jj) {
                _Float16 hi = (_Float16)mv[jj];
                Mh[ks][jj] = hi;
                Ml[ks][jj] = (_Float16)(mv[jj]-(float)hi);
            }
        }
        floatx4 acc[4];
        #pragma unroll
        for (int nt = 0; nt < 4; ++nt) {
            acc[nt] = (floatx4){0.f,0.f,0.f,0.f};
            #pragma unroll
            for (int ks = 0; ks < 2; ++ks) {
                acc[nt] = MFMA16(Mh[ks], W2r[nt][ks][0], acc[nt]);
                acc[nt] = MFMA16(Mh[ks], W2r[nt][ks][1], acc[nt]);
                acc[nt] = MFMA16(Ml[ks], W2r[nt][ks][0], acc[nt]);
            }
        }
        float om[4];
        #pragma unroll
        for (int nt = 0; nt < 4; ++nt) {
            float mr = fmaxf(fmaxf(acc[nt][0], acc[nt][1]),
                             fmaxf(acc[nt][2], acc[nt][3]));
            mr = fmaxf(mr, __shfl_xor(mr, 16, 64));
            mr = fmaxf(mr, __shfl_xor(mr, 32, 64));
            om[nt] = mr;
        }
        float val = (gid == 0) ? om[0] : (gid == 1) ? om[1]
                  : (gid == 2) ? om[2] : om[3];
        hout[(size_t)(i0+nn)*64 + gid*16 + m16] = val + b2v;
    }
}

// ---------------- mean-pool + output MLP ----------------
__global__ __launch_bounds__(256) void pool_kernel(
    const float* __restrict__ h,    // [N,64]
    const float* __restrict__ w1,   // [64,32]
    const float* __restrict__ b1,   // [32]
    const float* __restrict__ w2,   // [32,1]
    const float* __restrict__ b2,   // [1]
    float* __restrict__ out)        // [B]
{
    __shared__ float part[4][64];
    __shared__ float g[64];
    __shared__ float hid[32];
    int t = threadIdx.x;
    int o = t & 63, p = t >> 6;
    int b = blockIdx.x;
    const float* hb = h + (size_t)b*M_*H_;
    float s = 0.f;
    for (int m = p; m < M_; m += 4) s += hb[(size_t)m*64 + o];
    part[p][o] = s;
    __syncthreads();
    if (t < 64) g[t] = (part[0][t] + part[1][t] + part[2][t] + part[3][t]) * (1.f/M_);
    __syncthreads();
    if (t < 32) {
        float a = b1[t];
        for (int f = 0; f < 64; ++f) a += g[f] * w1[f*32 + t];
        hid[t] = fmaxf(a, 0.f);
    }
    __syncthreads();
    if (t == 0) {
        float a = b2[0];
        for (int f = 0; f < 32; ++f) a += hid[f] * w2[f];
        out[b] = a;
    }
}

extern "C" void kernel_launch(void* const* d_in, const int* in_sizes, int n_in,
                              void* d_out, int out_size, void* d_ws, size_t ws_size,
                              hipStream_t stream)
{
    (void)in_sizes; (void)n_in; (void)out_size; (void)ws_size;
    const float* x      = (const float*)d_in[0];
    const float* enc_w1 = (const float*)d_in[2];
    const float* enc_b1 = (const float*)d_in[3];
    const float* enc_w2 = (const float*)d_in[4];
    const float* enc_b2 = (const float*)d_in[5];
    const float* ec1_w1 = (const float*)d_in[6];
    const float* ec1_b1 = (const float*)d_in[7];
    const float* ec1_w2 = (const float*)d_in[8];
    const float* ec1_b2 = (const float*)d_in[9];
    const float* ec2_w1 = (const float*)d_in[10];
    const float* ec2_b1 = (const float*)d_in[11];
    const float* ec2_w2 = (const float*)d_in[12];
    const float* ec2_b2 = (const float*)d_in[13];
    const float* out_w1 = (const float*)d_in[14];
    const float* out_b1 = (const float*)d_in[15];
    const float* out_w2 = (const float*)d_in[16];
    const float* out_b2 = (const float*)d_in[17];

    // ws layout, 34.25 MB total. Region2 (16 MB) time-shared:
    //   (hhi|hlo) live producer->knn;  A lives gemmA->edge.  Never overlap.
    char* ws = (char*)d_ws;
    float*          h   = (float*)(ws);                                  // 16 MB
    char*           r2  = ws + (size_t)N_*64*4;                          // 16 MB
    _Float16*       hhi = (_Float16*)r2;                                 //  8 MB
    _Float16*       hlo = (_Float16*)(r2 + (size_t)N_*64*2);             //  8 MB
    float*          A   = (float*)r2;                                    // 16 MB (alias)
    unsigned short* idx = (unsigned short*)(ws + (size_t)N_*64*4*2);     //  2 MB
    float*          sq  = (float*)(ws + (size_t)N_*64*4*2 + (size_t)N_*16*2); // 256 KB

    enc_kernel<<<N_/256, 256, 0, stream>>>(x, enc_w1, enc_b1, enc_w2, enc_b2,
                                           h, hhi, hlo, sq);
    // layer 1
    knn_kernel <<<B_*16, 256, 0, stream>>>(hhi, hlo, sq, idx);
    gemmA_kernel<<<N_/256, 256, 0, stream>>>(h, ec1_w1, A);   // clobbers hhi/hlo (dead)
    edge_kernel<<<N_/64, 256, 0, stream>>>(h, A, idx, ec1_w1, ec1_b1, ec1_w2, ec1_b2, h);
    // layer 2
    convert_kernel<<<N_/64, 256, 0, stream>>>(h, hhi, hlo, sq); // clobbers A (dead)
    knn_kernel <<<B_*16, 256, 0, stream>>>(hhi, hlo, sq, idx);
    gemmA_kernel<<<N_/256, 256, 0, stream>>>(h, ec2_w1, A);
    edge_kernel<<<N_/64, 256, 0, stream>>>(h, A, idx, ec2_w1, ec2_b1, ec2_w2, ec2_b2, h);
    // pool + output MLP
    pool_kernel<<<B_, 256, 0, stream>>>(h, out_w1, out_b1, out_w2, out_b2, (float*)d_out);
}

// Round 8
// 355.799 us; speedup vs baseline: 1.1552x; 1.1552x over previous
//
#include <hip/hip_runtime.h>
#include <math.h>

#define B_ 64
#define M_ 1024
#define H_ 64
#define N_ (B_*M_)   // 65536

typedef _Float16 half8 __attribute__((ext_vector_type(8)));
typedef float  floatx4 __attribute__((ext_vector_type(4)));

#define MFMA16(a,b,c) __builtin_amdgcn_mfma_f32_16x16x32_f16(a,b,c,0,0,0)
#define MED3(a,b,c)   __builtin_amdgcn_fmed3f(a,b,c)

// ---------------- encoder: h = relu(relu(x@w1+b1)@w2+b2) (+ f16 split + sq) ------
__global__ __launch_bounds__(256) void enc_kernel(
    const float* __restrict__ x,     // [N,4]
    const float* __restrict__ w1,    // [4,32]
    const float* __restrict__ b1,    // [32]
    const float* __restrict__ w2,    // [32,64]
    const float* __restrict__ b2,    // [64]
    float* __restrict__ h,           // [N,64]
    _Float16* __restrict__ hhi,      // [N,64]
    _Float16* __restrict__ hlo,      // [N,64]
    float* __restrict__ sq)          // [N]
{
    __shared__ float sw1[4*32];
    __shared__ float sb1[32];
    __shared__ float sw2[32*64];
    __shared__ float sb2[64];
    int t = threadIdx.x;
    for (int i = t; i < 128; i += 256) sw1[i] = w1[i];
    if (t < 32) sb1[t] = b1[t];
    for (int i = t; i < 2048; i += 256) sw2[i] = w2[i];
    if (t < 64) sb2[t] = b2[t];
    __syncthreads();
    int n = blockIdx.x * 256 + t;
    float4 xv = *(const float4*)(x + (size_t)n*4);
    float hid[32];
    #pragma unroll
    for (int o = 0; o < 32; ++o) {
        float a = sb1[o] + xv.x*sw1[0*32+o] + xv.y*sw1[1*32+o]
                        + xv.z*sw1[2*32+o] + xv.w*sw1[3*32+o];
        hid[o] = fmaxf(a, 0.f);
    }
    float* hout = h + (size_t)n*64;
    float sqa = 0.f;
    #pragma unroll 4
    for (int oc = 0; oc < 16; ++oc) {
        float4 acc = make_float4(sb2[oc*4+0], sb2[oc*4+1], sb2[oc*4+2], sb2[oc*4+3]);
        #pragma unroll
        for (int f = 0; f < 32; ++f) {
            float4 w = *(const float4*)(sw2 + f*64 + oc*4);
            float hv = hid[f];
            acc.x += hv*w.x; acc.y += hv*w.y; acc.z += hv*w.z; acc.w += hv*w.w;
        }
        acc.x = fmaxf(acc.x,0.f); acc.y = fmaxf(acc.y,0.f);
        acc.z = fmaxf(acc.z,0.f); acc.w = fmaxf(acc.w,0.f);
        *(float4*)(hout + oc*4) = acc;
        sqa += acc.x*acc.x + acc.y*acc.y + acc.z*acc.z + acc.w*acc.w;
        union { _Float16 f[4]; uint2 u; } Hh, Hl;
        Hh.f[0]=(_Float16)acc.x; Hh.f[1]=(_Float16)acc.y;
        Hh.f[2]=(_Float16)acc.z; Hh.f[3]=(_Float16)acc.w;
        Hl.f[0]=(_Float16)(acc.x-(float)Hh.f[0]); Hl.f[1]=(_Float16)(acc.y-(float)Hh.f[1]);
        Hl.f[2]=(_Float16)(acc.z-(float)Hh.f[2]); Hl.f[3]=(_Float16)(acc.w-(float)Hh.f[3]);
        *(uint2*)(hhi + (size_t)n*64 + oc*4) = Hh.u;
        *(uint2*)(hlo + (size_t)n*64 + oc*4) = Hl.u;
    }
    sq[n] = sqa;
}

// ---------------- convert: h -> (hhi, hlo, sq)  (after edge layer 1) -------------
__global__ __launch_bounds__(256) void convert_kernel(
    const float* __restrict__ h,
    _Float16* __restrict__ hhi, _Float16* __restrict__ hlo,
    float* __restrict__ sq)
{
    int t = threadIdx.x, lane = t & 63, w = t >> 6;
    int base = blockIdx.x * 64 + w * 16;
    for (int it = 0; it < 16; ++it) {
        int i = base + it;
        float v = h[(size_t)i*64 + lane];
        _Float16 hi = (_Float16)v;
        _Float16 lo = (_Float16)(v - (float)hi);
        hhi[(size_t)i*64 + lane] = hi;
        hlo[(size_t)i*64 + lane] = lo;
        float s = v*v;
        #pragma unroll
        for (int off = 1; off < 64; off <<= 1) s += __shfl_xor(s, off, 64);
        if (lane == 0) sq[i] = s;
    }
}

// ---------------- A = h @ W1b  (W1b = rows 64..127 of w1) ----------------
__global__ __launch_bounds__(256) void gemmA_kernel(
    const float* __restrict__ h,
    const float* __restrict__ w1,   // [128,64]
    float* __restrict__ A)
{
    __shared__ float sw[64*64];
    int t = threadIdx.x;
    for (int idx = t; idx < 4096; idx += 256) sw[idx] = w1[4096 + idx];
    __syncthreads();
    int n = blockIdx.x * 256 + t;
    float4 hv[16];
    const float* src = h + (size_t)n*64;
    #pragma unroll
    for (int c = 0; c < 16; ++c) hv[c] = *(const float4*)(src + c*4);
    float* dst = A + (size_t)n*64;
    #pragma unroll 2
    for (int oc = 0; oc < 16; ++oc) {
        float4 acc = make_float4(0.f,0.f,0.f,0.f);
        #pragma unroll
        for (int f = 0; f < 64; ++f) {
            float xv = ((const float*)hv)[f];
            float4 w = *(const float4*)(sw + f*64 + oc*4);
            acc.x += xv*w.x; acc.y += xv*w.y; acc.z += xv*w.z; acc.w += xv*w.w;
        }
        *(float4*)(dst + oc*4) = acc;
    }
}

// ---------------- kNN v11 (measured best: 64.5us): 32-cand tiles, 32 q/wave ----
// Block = 128 queries (4 waves x 32 in 2 MFMA B-groups), grid = 512 blocks.
// All waves scan the graph's 1024 candidates from LDS tiles of 32 rows
// (hi+lo f16 split), double-buffered, XOR-swizzled (conflict-free ds_read_b128).
// Selection runs directly on the MFMA accumulator (C/D: col=lane&15=query,
// row=cand); top-16 via med3 insertion on packed keys (quantized 1+d^2 | idx).
__global__ __launch_bounds__(256, 2) void knn_kernel(
    const _Float16* __restrict__ hhi,
    const _Float16* __restrict__ hlo,
    const float* __restrict__ sqg,
    unsigned short* __restrict__ knn)    // [N,16]
{
    __shared__ __align__(16) _Float16 bufH[2][32*64];   // 2 x 4KB hi tiles
    __shared__ __align__(16) _Float16 bufL[2][32*64];   // 2 x 4KB lo tiles
    __shared__ __align__(16) float sqS[1024];           // 4KB
    __shared__ float md[128*65];                        // 33.3KB merge buffer

    int t = threadIdx.x, lane = t & 63, w = t >> 6;
    int bi = blockIdx.x;
    int g   = (bi & 7) | ((bi >> 6) << 3);  // 8 blocks/graph share bi%8 -> same XCD L2
    int qt8 = (bi >> 3) & 7;                // which 128-query slice of the graph
    const _Float16* hhig = hhi + (size_t)g*M_*64;
    const _Float16* hlog = hlo + (size_t)g*M_*64;
    const float*    sqb  = sqg + (size_t)g*M_;

    ((float4*)sqS)[t] = ((const float4*)sqb)[t];        // stage sq: 256 x 16B

    int m16 = lane & 15, gid = lane >> 4;
    int crow = gid*4, koct = gid*8;
    int sw = m16 & 7;

    // staging role: waves 0,1 -> hi tile, waves 2,3 -> lo tile (32 rows each)
    int u  = ((w & 1) << 6) | lane;         // 0..127 within role pair
    int rr = u >> 3;                        // row 0..15 (subtile 0; +16 for subtile 1)
    int gl = u & 7;                         // logical 16B granule (linear global read)
    int pp = gl ^ (rr & 7);                 // physical granule (XOR swizzle on write)
    const _Float16* srcb = (w < 2 ? hhig : hlog) + rr*64 + gl*8;
    _Float16* dst0 = (w < 2 ? bufH[0] : bufL[0]) + rr*64 + pp*8;
    _Float16* dst1 = (w < 2 ? bufH[1] : bufL[1]) + rr*64 + pp*8;

    // query fragments (B operand): 2 groups of 16 rows
    int qbase = qt8*128 + w*32;
    half8 Q0h0, Q0h1, Q0l0, Q0l1, Q1h0, Q1h1, Q1l0, Q1l1;
    {
        const _Float16* ph = hhig + (size_t)(qbase + m16)*64;
        const _Float16* pl = hlog + (size_t)(qbase + m16)*64;
        Q0h0 = *(const half8*)(ph + koct);
        Q0h1 = *(const half8*)(ph + 32 + koct);
        Q0l0 = *(const half8*)(pl + koct);
        Q0l1 = *(const half8*)(pl + 32 + koct);
        ph += 16*64; pl += 16*64;
        Q1h0 = *(const half8*)(ph + koct);
        Q1h1 = *(const half8*)(ph + 32 + koct);
        Q1l0 = *(const half8*)(pl + koct);
        Q1l1 = *(const half8*)(pl + 32 + koct);
    }

    float bd0[16], bd1[16];
    #pragma unroll
    for (int k = 0; k < 16; ++k) { bd0[k] = INFINITY; bd1[k] = INFINITY; }

    int ts0 = qt8*8 + w*2;      // global 16-cand subtile holding qg0's self
    int ts1 = ts0 + 1;          // ... and qg1's self

    // prologue: tile0 regs -> buf0; prefetch tiles 1,2 into regs
    float4 a0, a1, b0, b1;
    a0 = *(const float4*)(srcb);
    a1 = *(const float4*)(srcb + 1024);
    b0 = *(const float4*)(srcb + 2048);
    b1 = *(const float4*)(srcb + 3072);
    *(float4*)dst0 = a0;  *(float4*)(dst0 + 1024) = a1;
    a0 = *(const float4*)(srcb + 2*2048);
    a1 = *(const float4*)(srcb + 2*2048 + 1024);
    __syncthreads();                        // buf0 + sqS ready

    float c10 = 1.f + sqS[qbase + m16];
    float c11 = 1.f + sqS[qbase + 16 + m16];

    int o0 = m16*64 + ((gid ^ sw) * 8);     // swizzled frag offsets (ks0)
    int o1 = o0 ^ 32;                       // ks1 granule ^= 4

    auto insert4 = [&](float (&bdr)[16], floatx4 acc, float4 sqv,
                       unsigned cid, bool st, float c1v) {
        #pragma unroll
        for (int r = 0; r < 4; ++r) {
            float s  = fmaf(-2.f, acc[r], (&sqv.x)[r]);   // sq_j - 2 dot
            float t2 = c1v + s;                           // 1 + d^2  (>0)
            unsigned kb = (__float_as_uint(t2) & 0xFFFFFC00u) | (cid + r);
            float fk = __uint_as_float(kb);
            if (st && (crow + r) == m16) fk = INFINITY;   // self
            float nb0 = fminf(bdr[0], fk);
            #pragma unroll
            for (int k = 15; k >= 1; --k) bdr[k] = MED3(fk, bdr[k-1], bdr[k]);
            bdr[0] = nb0;
        }
    };

    auto compute = [&](int T, const _Float16* bh, const _Float16* bl) {
        #pragma unroll
        for (int s = 0; s < 2; ++s) {
            int ob = s*1024;
            half8 Ah0 = *(const half8*)(bh + ob + o0);
            half8 Ah1 = *(const half8*)(bh + ob + o1);
            half8 Al0 = *(const half8*)(bl + ob + o0);
            half8 Al1 = *(const half8*)(bl + ob + o1);
            float4 sqv = *(const float4*)(sqS + T*32 + s*16 + crow);
            unsigned cid = (unsigned)(T*32 + s*16 + crow);
            int ts = T*2 + s;
            floatx4 acc = {0.f, 0.f, 0.f, 0.f};
            acc = MFMA16(Ah0, Q0h0, acc);
            acc = MFMA16(Ah1, Q0h1, acc);
            acc = MFMA16(Ah0, Q0l0, acc);
            acc = MFMA16(Ah1, Q0l1, acc);
            acc = MFMA16(Al0, Q0h0, acc);
            acc = MFMA16(Al1, Q0h1, acc);
            insert4(bd0, acc, sqv, cid, ts == ts0, c10);
            floatx4 acc2 = {0.f, 0.f, 0.f, 0.f};
            acc2 = MFMA16(Ah0, Q1h0, acc2);
            acc2 = MFMA16(Ah1, Q1h1, acc2);
            acc2 = MFMA16(Ah0, Q1l0, acc2);
            acc2 = MFMA16(Ah1, Q1l1, acc2);
            acc2 = MFMA16(Al0, Q1h0, acc2);
            acc2 = MFMA16(Al1, Q1h1, acc2);
            insert4(bd1, acc2, sqv, cid, ts == ts1, c11);
        }
    };

    // main loop: 32 tiles, 2 per iteration; double-buffered LDS, raw barriers
    #pragma unroll 1
    for (int T = 0; T < 32; T += 2) {
        __builtin_amdgcn_s_barrier();                   // all done reading buf1
        *(float4*)dst1 = b0;  *(float4*)(dst1 + 1024) = b1;   // tile T+1 -> buf1
        { size_t o = (size_t)((T+3)&31)*2048;
          b0 = *(const float4*)(srcb + o);
          b1 = *(const float4*)(srcb + o + 1024); }
        asm volatile("s_waitcnt lgkmcnt(0)" ::: "memory");
        __builtin_amdgcn_s_barrier();                   // buf1 visible to all
        __builtin_amdgcn_sched_barrier(0);
        compute(T, bufH[0], bufL[0]);
        __builtin_amdgcn_s_barrier();                   // all done reading buf0
        *(float4*)dst0 = a0;  *(float4*)(dst0 + 1024) = a1;   // tile T+2 -> buf0
        { size_t o = (size_t)((T+4)&31)*2048;
          a0 = *(const float4*)(srcb + o);
          a1 = *(const float4*)(srcb + o + 1024); }
        asm volatile("s_waitcnt lgkmcnt(0)" ::: "memory");
        __builtin_amdgcn_s_barrier();                   // buf0 visible to all
        __builtin_amdgcn_sched_barrier(0);
        compute(T+1, bufH[1], bufL[1]);
    }

    // ---- merge 4 per-query-gid lists (64 keys/query); waves 0,1 extract ----
    __syncthreads();
    int qrow0 = w*32 + m16;
    #pragma unroll
    for (int k = 0; k < 16; ++k) {
        md[qrow0*65 + gid*16 + k]      = bd0[k];
        md[(qrow0+16)*65 + gid*16 + k] = bd1[k];
    }
    __syncthreads();
    if (w < 2) {
        int q = w*64 + lane;                 // query within block [0,128)
        float b2[16];
        #pragma unroll
        for (int k = 0; k < 16; ++k) b2[k] = INFINITY;
        const float* mrow = md + (size_t)q*65;
        #pragma unroll
        for (int c8 = 0; c8 < 8; ++c8) {
            float sv[8];
            #pragma unroll
            for (int j = 0; j < 8; ++j) sv[j] = mrow[c8*8 + j];
            #pragma unroll
            for (int j = 0; j < 8; ++j) {
                float s = sv[j];
                float nb0 = fminf(b2[0], s);
                #pragma unroll
                for (int k = 15; k >= 1; --k) b2[k] = MED3(s, b2[k-1], b2[k]);
                b2[0] = nb0;
            }
        }
        union { unsigned short us[16]; uint4 v4[2]; } o;
        #pragma unroll
        for (int k = 0; k < 16; ++k)
            o.us[k] = (unsigned short)(__float_as_uint(b2[k]) & 1023u);
        size_t gq = (size_t)g*M_ + qt8*128 + q;
        uint4* dst = (uint4*)(knn + gq*16);
        dst[0] = o.v4[0];
        dst[1] = o.v4[1];
    }
}

// ---------------- EdgeConv v4 (MFMA): optional fused mean-pool partials --------
// gsum == nullptr: write hout (layer 1).  gsum != nullptr (layer 2): skip the
// 16MB hout store entirely (h is dead after pooling) and emit per-block
// 64-channel partial sums into gsum[(g*16+qt)*64 + ch] (one 256B store/block).
__global__ __launch_bounds__(256) void edge_kernel(
    const float* __restrict__ h,     // [N,64] (in-place out OK: own rows read first)
    const float* __restrict__ A,     // [N,64]
    const unsigned short* __restrict__ knn, // [N,16] local idx
    const float* __restrict__ w1,    // [128,64]
    const float* __restrict__ b1,    // [64]
    const float* __restrict__ w2,    // [64,64]
    const float* __restrict__ b2,    // [64]
    float* __restrict__ hout,
    float* __restrict__ gsum)        // [B*16,64] partial sums or nullptr
{
    __shared__ __align__(16) _Float16 wdf[16*64*8];   // Wd B-frags (16 KB) -> part[]
    __shared__ __align__(16) _Float16 w2f[16*64*8];   // W2 B-frags (16 KB) -> Cs after
    float* CsB = (float*)w2f;                          // Cs[4][16][64] alias (16 KB)
    int t = threadIdx.x;
    for (int u = t; u < 512; u += 256) {
        int ulane = u & 63, nt = u >> 7, ks = (u >> 6) & 1;
        int n = nt*16 + (ulane & 15);
        int kbase = ks*32 + ((ulane >> 4) * 8);
        int fh = (((nt*2+ks)*2+0)*64 + ulane)*8;
        int fl = (((nt*2+ks)*2+1)*64 + ulane)*8;
        #pragma unroll
        for (int j = 0; j < 8; ++j) {
            int k = kbase + j;
            float vd = w1[k*64+n] - w1[4096 + k*64+n];
            _Float16 dh = (_Float16)vd;
            wdf[fh+j] = dh;
            wdf[fl+j] = (_Float16)(vd - (float)dh);
            float v2 = w2[k*64+n];
            _Float16 h2 = (_Float16)v2;
            w2f[fh+j] = h2;
            w2f[fl+j] = (_Float16)(v2 - (float)h2);
        }
    }
    __syncthreads();
    int lane = t & 63, wid = t >> 6;
    int m16 = lane & 15, gid = lane >> 4;
    int koct = gid*8, crow = gid*4;
    int bi = blockIdx.x;
    int g  = (bi & 7) | ((bi >> 7) << 3);    // XCD swizzle: graph's blocks share an XCD
    int qt = (bi >> 3) & 15;
    int i0 = g*M_ + qt*64 + wid*16;          // first node of this wave
    const float* Ab = A + (size_t)g*M_*H_;

    half8 W2r[4][2][2];
    #pragma unroll
    for (int nt = 0; nt < 4; ++nt)
        #pragma unroll
        for (int ks = 0; ks < 2; ++ks)
            #pragma unroll
            for (int p = 0; p < 2; ++p)
                W2r[nt][ks][p] = *(const half8*)&w2f[(((nt*2+ks)*2+p)*64+lane)*8];

    float b1v[4];
    #pragma unroll
    for (int nt = 0; nt < 4; ++nt) b1v[nt] = b1[nt*16+m16];
    float b2v = b2[gid*16+m16];
    __syncthreads();   // all waves done reading w2f -> safe to overwrite with Cs

    // ---- Phase 1: C tile = h(16 nodes) @ Wd + b1 -> CsB (over w2f) ----
    half8 Hh[2], Hl[2];
    #pragma unroll
    for (int ks = 0; ks < 2; ++ks) {
        const float* hp = h + (size_t)(i0+m16)*64 + ks*32 + koct;
        float4 v0 = *(const float4*)hp;
        float4 v1 = *(const float4*)(hp+4);
        float va[8] = {v0.x,v0.y,v0.z,v0.w,v1.x,v1.y,v1.z,v1.w};
        #pragma unroll
        for (int j = 0; j < 8; ++j) {
            _Float16 hi = (_Float16)va[j];
            Hh[ks][j] = hi;
            Hl[ks][j] = (_Float16)(va[j]-(float)hi);
        }
    }
    #pragma unroll
    for (int nt = 0; nt < 4; ++nt) {
        floatx4 acc = {b1v[nt], b1v[nt], b1v[nt], b1v[nt]};
        #pragma unroll
        for (int ks = 0; ks < 2; ++ks) {
            half8 wh = *(const half8*)&wdf[(((nt*2+ks)*2+0)*64+lane)*8];
            half8 wl = *(const half8*)&wdf[(((nt*2+ks)*2+1)*64+lane)*8];
            acc = MFMA16(Hh[ks], wh, acc);
            acc = MFMA16(Hh[ks], wl, acc);
            acc = MFMA16(Hl[ks], wh, acc);
        }
        #pragma unroll
        for (int r = 0; r < 4; ++r)
            CsB[((wid*16) + crow + r)*64 + nt*16 + m16] = acc[r];
    }
    __syncthreads();   // also: last read of wdf was Phase 1 -> reusable below

    // ---- Phase 2: per node, msg = relu(C + A_j), out = max_e msg@W2 + b2 ----
    const unsigned short* knb = knn + (size_t)i0*16;
    float ssum = 0.f;
    #pragma unroll 2
    for (int nn = 0; nn < 16; ++nn) {
        int j = knb[nn*16 + m16];
        const float* Ap = Ab + (size_t)j*64;
        half8 Mh[2], Ml[2];
        #pragma unroll
        for (int ks = 0; ks < 2; ++ks) {
            float4 a0 = *(const float4*)(Ap + ks*32 + koct);
            float4 a1 = *(const float4*)(Ap + ks*32 + koct + 4);
            const float* cp = &CsB[(wid*16 + nn)*64 + ks*32 + koct];
            float4 c0 = *(const float4*)cp;
            float4 c1 = *(const float4*)(cp+4);
            float mv[8] = {
                fmaxf(a0.x+c0.x,0.f), fmaxf(a0.y+c0.y,0.f),
                fmaxf(a0.z+c0.z,0.f), fmaxf(a0.w+c0.w,0.f),
                fmaxf(a1.x+c1.x,0.f), fmaxf(a1.y+c1.y,0.f),
                fmaxf(a1.z+c1.z,0.f), fmaxf(a1.w+c1.w,0.f)};
            #pragma unroll
            for (int jj = 0; jj < 8; ++jj) {
                _Float16 hi = (_Float16)mv[jj];
                Mh[ks][jj] = hi;
                Ml[ks][jj] = (_Float16)(mv[jj]-(float)hi);
            }
        }
        floatx4 acc[4];
        #pragma unroll
        for (int nt = 0; nt < 4; ++nt) {
            acc[nt] = (floatx4){0.f,0.f,0.f,0.f};
            #pragma unroll
            for (int ks = 0; ks < 2; ++ks) {
                acc[nt] = MFMA16(Mh[ks], W2r[nt][ks][0], acc[nt]);
                acc[nt] = MFMA16(Mh[ks], W2r[nt][ks][1], acc[nt]);
                acc[nt] = MFMA16(Ml[ks], W2r[nt][ks][0], acc[nt]);
            }
        }
        float om[4];
        #pragma unroll
        for (int nt = 0; nt < 4; ++nt) {
            float mr = fmaxf(fmaxf(acc[nt][0], acc[nt][1]),
                             fmaxf(acc[nt][2], acc[nt][3]));
            mr = fmaxf(mr, __shfl_xor(mr, 16, 64));
            mr = fmaxf(mr, __shfl_xor(mr, 32, 64));
            om[nt] = mr;
        }
        float val = (gid == 0) ? om[0] : (gid == 1) ? om[1]
                  : (gid == 2) ? om[2] : om[3];
        float outv = val + b2v;
        if (gsum) ssum += outv;
        else hout[(size_t)(i0+nn)*64 + gid*16 + m16] = outv;
    }

    if (gsum) {   // per-block 64-ch partial sum over its 64 nodes
        float* part = (float*)wdf;               // wdf dead after Phase 1
        part[wid*64 + gid*16 + m16] = ssum;
        __syncthreads();
        if (t < 64) {
            float tot = part[t] + part[64+t] + part[128+t] + part[192+t];
            gsum[(size_t)(g*16 + qt)*64 + t] = tot;
        }
    }
}

// ---------------- final pool: partial sums -> mean -> output MLP ----------------
__global__ __launch_bounds__(64) void poolf_kernel(
    const float* __restrict__ gsum, // [B*16,64]
    const float* __restrict__ w1,   // [64,32]
    const float* __restrict__ b1,   // [32]
    const float* __restrict__ w2,   // [32,1]
    const float* __restrict__ b2,   // [1]
    float* __restrict__ out)        // [B]
{
    __shared__ float g[64];
    __shared__ float hid[32];
    int t = threadIdx.x;
    int b = blockIdx.x;
    float s = 0.f;
    #pragma unroll
    for (int k = 0; k < 16; ++k) s += gsum[(size_t)(b*16 + k)*64 + t];
    g[t] = s * (1.f/M_);
    __syncthreads();
    if (t < 32) {
        float a = b1[t];
        for (int f = 0; f < 64; ++f) a += g[f] * w1[f*32 + t];
        hid[t] = fmaxf(a, 0.f);
    }
    __syncthreads();
    if (t == 0) {
        float a = b2[0];
        for (int f = 0; f < 32; ++f) a += hid[f] * w2[f];
        out[b] = a;
    }
}

extern "C" void kernel_launch(void* const* d_in, const int* in_sizes, int n_in,
                              void* d_out, int out_size, void* d_ws, size_t ws_size,
                              hipStream_t stream)
{
    (void)in_sizes; (void)n_in; (void)out_size; (void)ws_size;
    const float* x      = (const float*)d_in[0];
    const float* enc_w1 = (const float*)d_in[2];
    const float* enc_b1 = (const float*)d_in[3];
    const float* enc_w2 = (const float*)d_in[4];
    const float* enc_b2 = (const float*)d_in[5];
    const float* ec1_w1 = (const float*)d_in[6];
    const float* ec1_b1 = (const float*)d_in[7];
    const float* ec1_w2 = (const float*)d_in[8];
    const float* ec1_b2 = (const float*)d_in[9];
    const float* ec2_w1 = (const float*)d_in[10];
    const float* ec2_b1 = (const float*)d_in[11];
    const float* ec2_w2 = (const float*)d_in[12];
    const float* ec2_b2 = (const float*)d_in[13];
    const float* out_w1 = (const float*)d_in[14];
    const float* out_b1 = (const float*)d_in[15];
    const float* out_w2 = (const float*)d_in[16];
    const float* out_b2 = (const float*)d_in[17];

    // ws layout, 34.25 MB total. Region2 (16 MB) time-shared:
    //   (hhi|hlo) live producer->knn;  A lives gemmA->edge.  Never overlap.
    // sq region (256 KB) is dead after knn2 -> reused as gsum (exactly 256 KB).
    char* ws = (char*)d_ws;
    float*          h   = (float*)(ws);                                  // 16 MB
    char*           r2  = ws + (size_t)N_*64*4;                          // 16 MB
    _Float16*       hhi = (_Float16*)r2;                                 //  8 MB
    _Float16*       hlo = (_Float16*)(r2 + (size_t)N_*64*2);             //  8 MB
    float*          A   = (float*)r2;                                    // 16 MB (alias)
    unsigned short* idx = (unsigned short*)(ws + (size_t)N_*64*4*2);     //  2 MB
    float*          sq  = (float*)(ws + (size_t)N_*64*4*2 + (size_t)N_*16*2); // 256 KB
    float*          gsum = sq;    // [B*16,64] partial sums (sq dead after knn2)

    enc_kernel<<<N_/256, 256, 0, stream>>>(x, enc_w1, enc_b1, enc_w2, enc_b2,
                                           h, hhi, hlo, sq);
    // layer 1
    knn_kernel <<<B_*8, 256, 0, stream>>>(hhi, hlo, sq, idx);
    gemmA_kernel<<<N_/256, 256, 0, stream>>>(h, ec1_w1, A);   // clobbers hhi/hlo (dead)
    edge_kernel<<<N_/64, 256, 0, stream>>>(h, A, idx, ec1_w1, ec1_b1, ec1_w2, ec1_b2,
                                           h, nullptr);
    // layer 2
    convert_kernel<<<N_/64, 256, 0, stream>>>(h, hhi, hlo, sq); // clobbers A (dead)
    knn_kernel <<<B_*8, 256, 0, stream>>>(hhi, hlo, sq, idx);
    gemmA_kernel<<<N_/256, 256, 0, stream>>>(h, ec2_w1, A);
    edge_kernel<<<N_/64, 256, 0, stream>>>(h, A, idx, ec2_w1, ec2_b1, ec2_w2, ec2_b2,
                                           h, gsum);          // fused pool partials
    // final: partial sums -> mean -> output MLP
    poolf_kernel<<<B_, 64, 0, stream>>>(gsum, out_w1, out_b1, out_w2, out_b2,
                                        (float*)d_out);
}

// Round 9
// 355.617 us; speedup vs baseline: 1.1557x; 1.0005x over previous
//
#include <hip/hip_runtime.h>
#include <math.h>

#define B_ 64
#define M_ 1024
#define H_ 64
#define N_ (B_*M_)   // 65536

typedef _Float16 half8 __attribute__((ext_vector_type(8)));
typedef float  floatx4 __attribute__((ext_vector_type(4)));

#define MFMA16(a,b,c) __builtin_amdgcn_mfma_f32_16x16x32_f16(a,b,c,0,0,0)
#define MED3(a,b,c)   __builtin_amdgcn_fmed3f(a,b,c)

// ---------------- encoder: h = relu(relu(x@w1+b1)@w2+b2) -> (hhi,hlo,sq) --------
// h is stored ONLY as the f16 hi/lo split (hi+lo ~ fp32-exact); no f32 copy.
__global__ __launch_bounds__(256) void enc_kernel(
    const float* __restrict__ x,     // [N,4]
    const float* __restrict__ w1,    // [4,32]
    const float* __restrict__ b1,    // [32]
    const float* __restrict__ w2,    // [32,64]
    const float* __restrict__ b2,    // [64]
    _Float16* __restrict__ hhi,      // [N,64]
    _Float16* __restrict__ hlo,      // [N,64]
    float* __restrict__ sq)          // [N]
{
    __shared__ float sw1[4*32];
    __shared__ float sb1[32];
    __shared__ float sw2[32*64];
    __shared__ float sb2[64];
    int t = threadIdx.x;
    for (int i = t; i < 128; i += 256) sw1[i] = w1[i];
    if (t < 32) sb1[t] = b1[t];
    for (int i = t; i < 2048; i += 256) sw2[i] = w2[i];
    if (t < 64) sb2[t] = b2[t];
    __syncthreads();
    int n = blockIdx.x * 256 + t;
    float4 xv = *(const float4*)(x + (size_t)n*4);
    float hid[32];
    #pragma unroll
    for (int o = 0; o < 32; ++o) {
        float a = sb1[o] + xv.x*sw1[0*32+o] + xv.y*sw1[1*32+o]
                        + xv.z*sw1[2*32+o] + xv.w*sw1[3*32+o];
        hid[o] = fmaxf(a, 0.f);
    }
    float sqa = 0.f;
    #pragma unroll 4
    for (int oc = 0; oc < 16; ++oc) {
        float4 acc = make_float4(sb2[oc*4+0], sb2[oc*4+1], sb2[oc*4+2], sb2[oc*4+3]);
        #pragma unroll
        for (int f = 0; f < 32; ++f) {
            float4 w = *(const float4*)(sw2 + f*64 + oc*4);
            float hv = hid[f];
            acc.x += hv*w.x; acc.y += hv*w.y; acc.z += hv*w.z; acc.w += hv*w.w;
        }
        acc.x = fmaxf(acc.x,0.f); acc.y = fmaxf(acc.y,0.f);
        acc.z = fmaxf(acc.z,0.f); acc.w = fmaxf(acc.w,0.f);
        sqa += acc.x*acc.x + acc.y*acc.y + acc.z*acc.z + acc.w*acc.w;
        union { _Float16 f[4]; uint2 u; } Hh, Hl;
        Hh.f[0]=(_Float16)acc.x; Hh.f[1]=(_Float16)acc.y;
        Hh.f[2]=(_Float16)acc.z; Hh.f[3]=(_Float16)acc.w;
        Hl.f[0]=(_Float16)(acc.x-(float)Hh.f[0]); Hl.f[1]=(_Float16)(acc.y-(float)Hh.f[1]);
        Hl.f[2]=(_Float16)(acc.z-(float)Hh.f[2]); Hl.f[3]=(_Float16)(acc.w-(float)Hh.f[3]);
        *(uint2*)(hhi + (size_t)n*64 + oc*4) = Hh.u;
        *(uint2*)(hlo + (size_t)n*64 + oc*4) = Hl.u;
    }
    sq[n] = sqa;
}

// ---------------- A = h @ W1b  (MFMA, hi/lo split; W1b = rows 64..127) ----------
__global__ __launch_bounds__(256) void gemmA_kernel(
    const _Float16* __restrict__ hhi,
    const _Float16* __restrict__ hlo,
    const float* __restrict__ w1,   // [128,64]
    float* __restrict__ A)
{
    __shared__ __align__(16) _Float16 wf[16*64*8];   // W1b B-frags hi/lo (16 KB)
    int t = threadIdx.x;
    for (int u = t; u < 512; u += 256) {
        int ulane = u & 63, nt = u >> 7, ks = (u >> 6) & 1;
        int n = nt*16 + (ulane & 15);
        int kbase = ks*32 + ((ulane >> 4) * 8);
        int fh = (((nt*2+ks)*2+0)*64 + ulane)*8;
        int fl = (((nt*2+ks)*2+1)*64 + ulane)*8;
        #pragma unroll
        for (int j = 0; j < 8; ++j) {
            int k = kbase + j;
            float v = w1[4096 + k*64 + n];
            _Float16 hi = (_Float16)v;
            wf[fh+j] = hi;
            wf[fl+j] = (_Float16)(v - (float)hi);
        }
    }
    __syncthreads();
    int lane = t & 63, wid = t >> 6;
    int m16 = lane & 15, gid = lane >> 4;
    int koct = gid*8, crow = gid*4;
    int n0 = blockIdx.x*256 + wid*64;
    #pragma unroll
    for (int ng = 0; ng < 4; ++ng) {
        int nb = n0 + ng*16;
        half8 Hh[2], Hl[2];
        #pragma unroll
        for (int ks = 0; ks < 2; ++ks) {
            Hh[ks] = *(const half8*)(hhi + (size_t)(nb+m16)*64 + ks*32 + koct);
            Hl[ks] = *(const half8*)(hlo + (size_t)(nb+m16)*64 + ks*32 + koct);
        }
        #pragma unroll
        for (int nt = 0; nt < 4; ++nt) {
            floatx4 acc = {0.f,0.f,0.f,0.f};
            #pragma unroll
            for (int ks = 0; ks < 2; ++ks) {
                half8 wh = *(const half8*)&wf[(((nt*2+ks)*2+0)*64+lane)*8];
                half8 wl = *(const half8*)&wf[(((nt*2+ks)*2+1)*64+lane)*8];
                acc = MFMA16(Hh[ks], wh, acc);
                acc = MFMA16(Hh[ks], wl, acc);
                acc = MFMA16(Hl[ks], wh, acc);
            }
            #pragma unroll
            for (int r = 0; r < 4; ++r)
                A[(size_t)(nb+crow+r)*64 + nt*16 + m16] = acc[r];
        }
    }
}

// ---------------- kNN v11 (measured best: ~65us): 32-cand tiles, 32 q/wave ----
__global__ __launch_bounds__(256, 2) void knn_kernel(
    const _Float16* __restrict__ hhi,
    const _Float16* __restrict__ hlo,
    const float* __restrict__ sqg,
    unsigned short* __restrict__ knn)    // [N,16]
{
    __shared__ __align__(16) _Float16 bufH[2][32*64];   // 2 x 4KB hi tiles
    __shared__ __align__(16) _Float16 bufL[2][32*64];   // 2 x 4KB lo tiles
    __shared__ __align__(16) float sqS[1024];           // 4KB
    __shared__ float md[128*65];                        // 33.3KB merge buffer

    int t = threadIdx.x, lane = t & 63, w = t >> 6;
    int bi = blockIdx.x;
    int g   = (bi & 7) | ((bi >> 6) << 3);  // 8 blocks/graph share bi%8 -> same XCD L2
    int qt8 = (bi >> 3) & 7;                // which 128-query slice of the graph
    const _Float16* hhig = hhi + (size_t)g*M_*64;
    const _Float16* hlog = hlo + (size_t)g*M_*64;
    const float*    sqb  = sqg + (size_t)g*M_;

    ((float4*)sqS)[t] = ((const float4*)sqb)[t];        // stage sq: 256 x 16B

    int m16 = lane & 15, gid = lane >> 4;
    int crow = gid*4, koct = gid*8;
    int sw = m16 & 7;

    // staging role: waves 0,1 -> hi tile, waves 2,3 -> lo tile (32 rows each)
    int u  = ((w & 1) << 6) | lane;         // 0..127 within role pair
    int rr = u >> 3;                        // row 0..15 (subtile 0; +16 for subtile 1)
    int gl = u & 7;                         // logical 16B granule (linear global read)
    int pp = gl ^ (rr & 7);                 // physical granule (XOR swizzle on write)
    const _Float16* srcb = (w < 2 ? hhig : hlog) + rr*64 + gl*8;
    _Float16* dst0 = (w < 2 ? bufH[0] : bufL[0]) + rr*64 + pp*8;
    _Float16* dst1 = (w < 2 ? bufH[1] : bufL[1]) + rr*64 + pp*8;

    // query fragments (B operand): 2 groups of 16 rows
    int qbase = qt8*128 + w*32;
    half8 Q0h0, Q0h1, Q0l0, Q0l1, Q1h0, Q1h1, Q1l0, Q1l1;
    {
        const _Float16* ph = hhig + (size_t)(qbase + m16)*64;
        const _Float16* pl = hlog + (size_t)(qbase + m16)*64;
        Q0h0 = *(const half8*)(ph + koct);
        Q0h1 = *(const half8*)(ph + 32 + koct);
        Q0l0 = *(const half8*)(pl + koct);
        Q0l1 = *(const half8*)(pl + 32 + koct);
        ph += 16*64; pl += 16*64;
        Q1h0 = *(const half8*)(ph + koct);
        Q1h1 = *(const half8*)(ph + 32 + koct);
        Q1l0 = *(const half8*)(pl + koct);
        Q1l1 = *(const half8*)(pl + 32 + koct);
    }

    float bd0[16], bd1[16];
    #pragma unroll
    for (int k = 0; k < 16; ++k) { bd0[k] = INFINITY; bd1[k] = INFINITY; }

    int ts0 = qt8*8 + w*2;      // global 16-cand subtile holding qg0's self
    int ts1 = ts0 + 1;          // ... and qg1's self

    // prologue: tile0 regs -> buf0; prefetch tiles 1,2 into regs
    float4 a0, a1, b0, b1;
    a0 = *(const float4*)(srcb);
    a1 = *(const float4*)(srcb + 1024);
    b0 = *(const float4*)(srcb + 2048);
    b1 = *(const float4*)(srcb + 3072);
    *(float4*)dst0 = a0;  *(float4*)(dst0 + 1024) = a1;
    a0 = *(const float4*)(srcb + 2*2048);
    a1 = *(const float4*)(srcb + 2*2048 + 1024);
    __syncthreads();                        // buf0 + sqS ready

    float c10 = 1.f + sqS[qbase + m16];
    float c11 = 1.f + sqS[qbase + 16 + m16];

    int o0 = m16*64 + ((gid ^ sw) * 8);     // swizzled frag offsets (ks0)
    int o1 = o0 ^ 32;                       // ks1 granule ^= 4

    auto insert4 = [&](float (&bdr)[16], floatx4 acc, float4 sqv,
                       unsigned cid, bool st, float c1v) {
        #pragma unroll
        for (int r = 0; r < 4; ++r) {
            float s  = fmaf(-2.f, acc[r], (&sqv.x)[r]);   // sq_j - 2 dot
            float t2 = c1v + s;                           // 1 + d^2  (>0)
            unsigned kb = (__float_as_uint(t2) & 0xFFFFFC00u) | (cid + r);
            float fk = __uint_as_float(kb);
            if (st && (crow + r) == m16) fk = INFINITY;   // self
            float nb0 = fminf(bdr[0], fk);
            #pragma unroll
            for (int k = 15; k >= 1; --k) bdr[k] = MED3(fk, bdr[k-1], bdr[k]);
            bdr[0] = nb0;
        }
    };

    auto compute = [&](int T, const _Float16* bh, const _Float16* bl) {
        #pragma unroll
        for (int s = 0; s < 2; ++s) {
            int ob = s*1024;
            half8 Ah0 = *(const half8*)(bh + ob + o0);
            half8 Ah1 = *(const half8*)(bh + ob + o1);
            half8 Al0 = *(const half8*)(bl + ob + o0);
            half8 Al1 = *(const half8*)(bl + ob + o1);
            float4 sqv = *(const float4*)(sqS + T*32 + s*16 + crow);
            unsigned cid = (unsigned)(T*32 + s*16 + crow);
            int ts = T*2 + s;
            floatx4 acc = {0.f, 0.f, 0.f, 0.f};
            acc = MFMA16(Ah0, Q0h0, acc);
            acc = MFMA16(Ah1, Q0h1, acc);
            acc = MFMA16(Ah0, Q0l0, acc);
            acc = MFMA16(Ah1, Q0l1, acc);
            acc = MFMA16(Al0, Q0h0, acc);
            acc = MFMA16(Al1, Q0h1, acc);
            insert4(bd0, acc, sqv, cid, ts == ts0, c10);
            floatx4 acc2 = {0.f, 0.f, 0.f, 0.f};
            acc2 = MFMA16(Ah0, Q1h0, acc2);
            acc2 = MFMA16(Ah1, Q1h1, acc2);
            acc2 = MFMA16(Ah0, Q1l0, acc2);
            acc2 = MFMA16(Ah1, Q1l1, acc2);
            acc2 = MFMA16(Al0, Q1h0, acc2);
            acc2 = MFMA16(Al1, Q1h1, acc2);
            insert4(bd1, acc2, sqv, cid, ts == ts1, c11);
        }
    };

    // main loop: 32 tiles, 2 per iteration; double-buffered LDS, raw barriers
    #pragma unroll 1
    for (int T = 0; T < 32; T += 2) {
        __builtin_amdgcn_s_barrier();                   // all done reading buf1
        *(float4*)dst1 = b0;  *(float4*)(dst1 + 1024) = b1;   // tile T+1 -> buf1
        { size_t o = (size_t)((T+3)&31)*2048;
          b0 = *(const float4*)(srcb + o);
          b1 = *(const float4*)(srcb + o + 1024); }
        asm volatile("s_waitcnt lgkmcnt(0)" ::: "memory");
        __builtin_amdgcn_s_barrier();                   // buf1 visible to all
        __builtin_amdgcn_sched_barrier(0);
        compute(T, bufH[0], bufL[0]);
        __builtin_amdgcn_s_barrier();                   // all done reading buf0
        *(float4*)dst0 = a0;  *(float4*)(dst0 + 1024) = a1;   // tile T+2 -> buf0
        { size_t o = (size_t)((T+4)&31)*2048;
          a0 = *(const float4*)(srcb + o);
          a1 = *(const float4*)(srcb + o + 1024); }
        asm volatile("s_waitcnt lgkmcnt(0)" ::: "memory");
        __builtin_amdgcn_s_barrier();                   // buf0 visible to all
        __builtin_amdgcn_sched_barrier(0);
        compute(T+1, bufH[1], bufL[1]);
    }

    // ---- merge 4 per-query-gid lists (64 keys/query); waves 0,1 extract ----
    __syncthreads();
    int qrow0 = w*32 + m16;
    #pragma unroll
    for (int k = 0; k < 16; ++k) {
        md[qrow0*65 + gid*16 + k]      = bd0[k];
        md[(qrow0+16)*65 + gid*16 + k] = bd1[k];
    }
    __syncthreads();
    if (w < 2) {
        int q = w*64 + lane;                 // query within block [0,128)
        float b2[16];
        #pragma unroll
        for (int k = 0; k < 16; ++k) b2[k] = INFINITY;
        const float* mrow = md + (size_t)q*65;
        #pragma unroll
        for (int c8 = 0; c8 < 8; ++c8) {
            float sv[8];
            #pragma unroll
            for (int j = 0; j < 8; ++j) sv[j] = mrow[c8*8 + j];
            #pragma unroll
            for (int j = 0; j < 8; ++j) {
                float s = sv[j];
                float nb0 = fminf(b2[0], s);
                #pragma unroll
                for (int k = 15; k >= 1; --k) b2[k] = MED3(s, b2[k-1], b2[k]);
                b2[0] = nb0;
            }
        }
        union { unsigned short us[16]; uint4 v4[2]; } o;
        #pragma unroll
        for (int k = 0; k < 16; ++k)
            o.us[k] = (unsigned short)(__float_as_uint(b2[k]) & 1023u);
        size_t gq = (size_t)g*M_ + qt8*128 + q;
        uint4* dst = (uint4*)(knn + gq*16);
        dst[0] = o.v4[0];
        dst[1] = o.v4[1];
    }
}

// ---------------- EdgeConv v5: hi/lo input, in-place hi/lo+sq OR fused pool ----
// Layer 1 (gsum==nullptr): reads own rows from (hhi,hlo), writes own rows back
// in place (hi/lo split) + per-node sq for the next kNN.  Layer 2 (gsum set):
// emits only per-block 64-ch partial sums. hhi/hlo intentionally NOT restrict
// (in-place update of own rows; all reads precede writes via data deps).
__global__ __launch_bounds__(256) void edge_kernel(
    _Float16* hhi,                   // [N,64] in/out (own rows only)
    _Float16* hlo,                   // [N,64] in/out
    const float* __restrict__ A,     // [N,64]
    const unsigned short* __restrict__ knn, // [N,16] local idx
    const float* __restrict__ w1,    // [128,64]
    const float* __restrict__ b1,    // [64]
    const float* __restrict__ w2,    // [64,64]
    const float* __restrict__ b2,    // [64]
    float* __restrict__ sqout,       // [N] (layer 1) or unused
    float* __restrict__ gsum)        // [B*16,64] partial sums or nullptr
{
    __shared__ __align__(16) _Float16 wdf[16*64*8];   // Wd B-frags (16 KB) -> part[]
    __shared__ __align__(16) _Float16 w2f[16*64*8];   // W2 B-frags (16 KB) -> Cs after
    float* CsB = (float*)w2f;                          // Cs[4][16][64] alias (16 KB)
    int t = threadIdx.x;
    for (int u = t; u < 512; u += 256) {
        int ulane = u & 63, nt = u >> 7, ks = (u >> 6) & 1;
        int n = nt*16 + (ulane & 15);
        int kbase = ks*32 + ((ulane >> 4) * 8);
        int fh = (((nt*2+ks)*2+0)*64 + ulane)*8;
        int fl = (((nt*2+ks)*2+1)*64 + ulane)*8;
        #pragma unroll
        for (int j = 0; j < 8; ++j) {
            int k = kbase + j;
            float vd = w1[k*64+n] - w1[4096 + k*64+n];
            _Float16 dh = (_Float16)vd;
            wdf[fh+j] = dh;
            wdf[fl+j] = (_Float16)(vd - (float)dh);
            float v2 = w2[k*64+n];
            _Float16 h2 = (_Float16)v2;
            w2f[fh+j] = h2;
            w2f[fl+j] = (_Float16)(v2 - (float)h2);
        }
    }
    __syncthreads();
    int lane = t & 63, wid = t >> 6;
    int m16 = lane & 15, gid = lane >> 4;
    int koct = gid*8, crow = gid*4;
    int bi = blockIdx.x;
    int g  = (bi & 7) | ((bi >> 7) << 3);    // XCD swizzle: graph's blocks share an XCD
    int qt = (bi >> 3) & 15;
    int i0 = g*M_ + qt*64 + wid*16;          // first node of this wave
    const float* Ab = A + (size_t)g*M_*H_;

    half8 W2r[4][2][2];
    #pragma unroll
    for (int nt = 0; nt < 4; ++nt)
        #pragma unroll
        for (int ks = 0; ks < 2; ++ks)
            #pragma unroll
            for (int p = 0; p < 2; ++p)
                W2r[nt][ks][p] = *(const half8*)&w2f[(((nt*2+ks)*2+p)*64+lane)*8];

    float b1v[4];
    #pragma unroll
    for (int nt = 0; nt < 4; ++nt) b1v[nt] = b1[nt*16+m16];
    float b2v = b2[gid*16+m16];
    __syncthreads();   // all waves done reading w2f -> safe to overwrite with Cs

    // ---- Phase 1: C tile = h(16 nodes) @ Wd + b1 -> CsB (over w2f) ----
    half8 Hh[2], Hl[2];
    #pragma unroll
    for (int ks = 0; ks < 2; ++ks) {
        Hh[ks] = *(const half8*)(hhi + (size_t)(i0+m16)*64 + ks*32 + koct);
        Hl[ks] = *(const half8*)(hlo + (size_t)(i0+m16)*64 + ks*32 + koct);
    }
    #pragma unroll
    for (int nt = 0; nt < 4; ++nt) {
        floatx4 acc = {b1v[nt], b1v[nt], b1v[nt], b1v[nt]};
        #pragma unroll
        for (int ks = 0; ks < 2; ++ks) {
            half8 wh = *(const half8*)&wdf[(((nt*2+ks)*2+0)*64+lane)*8];
            half8 wl = *(const half8*)&wdf[(((nt*2+ks)*2+1)*64+lane)*8];
            acc = MFMA16(Hh[ks], wh, acc);
            acc = MFMA16(Hh[ks], wl, acc);
            acc = MFMA16(Hl[ks], wh, acc);
        }
        #pragma unroll
        for (int r = 0; r < 4; ++r)
            CsB[((wid*16) + crow + r)*64 + nt*16 + m16] = acc[r];
    }
    __syncthreads();   // wdf dead after Phase 1 -> reusable below

    // ---- Phase 2: per node, msg = relu(C + A_j), out = max_e msg@W2 + b2 ----
    const unsigned short* knb = knn + (size_t)i0*16;
    float ssum = 0.f;
    #pragma unroll 2
    for (int nn = 0; nn < 16; ++nn) {
        int j = knb[nn*16 + m16];
        const float* Ap = Ab + (size_t)j*64;
        half8 Mh[2], Ml[2];
        #pragma unroll
        for (int ks = 0; ks < 2; ++ks) {
            float4 a0 = *(const float4*)(Ap + ks*32 + koct);
            float4 a1 = *(const float4*)(Ap + ks*32 + koct + 4);
            const float* cp = &CsB[(wid*16 + nn)*64 + ks*32 + koct];
            float4 c0 = *(const float4*)cp;
            float4 c1 = *(const float4*)(cp+4);
            float mv[8] = {
                fmaxf(a0.x+c0.x,0.f), fmaxf(a0.y+c0.y,0.f),
                fmaxf(a0.z+c0.z,0.f), fmaxf(a0.w+c0.w,0.f),
                fmaxf(a1.x+c1.x,0.f), fmaxf(a1.y+c1.y,0.f),
                fmaxf(a1.z+c1.z,0.f), fmaxf(a1.w+c1.w,0.f)};
            #pragma unroll
            for (int jj = 0; jj < 8; ++jj) {
                _Float16 hi = (_Float16)mv[jj];
                Mh[ks][jj] = hi;
                Ml[ks][jj] = (_Float16)(mv[jj]-(float)hi);
            }
        }
        floatx4 acc[4];
        #pragma unroll
        for (int nt = 0; nt < 4; ++nt) {
            acc[nt] = (floatx4){0.f,0.f,0.f,0.f};
            #pragma unroll
            for (int ks = 0; ks < 2; ++ks) {
                acc[nt] = MFMA16(Mh[ks], W2r[nt][ks][0], acc[nt]);
                acc[nt] = MFMA16(Mh[ks], W2r[nt][ks][1], acc[nt]);
                acc[nt] = MFMA16(Ml[ks], W2r[nt][ks][0], acc[nt]);
            }
        }
        float om[4];
        #pragma unroll
        for (int nt = 0; nt < 4; ++nt) {
            float mr = fmaxf(fmaxf(acc[nt][0], acc[nt][1]),
                             fmaxf(acc[nt][2], acc[nt][3]));
            mr = fmaxf(mr, __shfl_xor(mr, 16, 64));
            mr = fmaxf(mr, __shfl_xor(mr, 32, 64));
            om[nt] = mr;
        }
        float val = (gid == 0) ? om[0] : (gid == 1) ? om[1]
                  : (gid == 2) ? om[2] : om[3];
        float outv = val + b2v;
        if (gsum) {
            ssum += outv;
        } else {
            // in-place hi/lo split of own row + per-node sq (wave reduce)
            _Float16 hi = (_Float16)outv;
            hhi[(size_t)(i0+nn)*64 + gid*16 + m16] = hi;
            hlo[(size_t)(i0+nn)*64 + gid*16 + m16] = (_Float16)(outv - (float)hi);
            float s2 = outv*outv;
            #pragma unroll
            for (int off = 1; off < 64; off <<= 1) s2 += __shfl_xor(s2, off, 64);
            if (lane == 0) sqout[i0+nn] = s2;
        }
    }

    if (gsum) {   // per-block 64-ch partial sum over its 64 nodes
        float* part = (float*)wdf;               // wdf dead after Phase 1
        part[wid*64 + gid*16 + m16] = ssum;
        __syncthreads();
        if (t < 64) {
            float tot = part[t] + part[64+t] + part[128+t] + part[192+t];
            gsum[(size_t)(g*16 + qt)*64 + t] = tot;
        }
    }
}

// ---------------- final pool: partial sums -> mean -> output MLP ----------------
__global__ __launch_bounds__(64) void poolf_kernel(
    const float* __restrict__ gsum, // [B*16,64]
    const float* __restrict__ w1,   // [64,32]
    const float* __restrict__ b1,   // [32]
    const float* __restrict__ w2,   // [32,1]
    const float* __restrict__ b2,   // [1]
    float* __restrict__ out)        // [B]
{
    __shared__ float g[64];
    __shared__ float hid[32];
    int t = threadIdx.x;
    int b = blockIdx.x;
    float s = 0.f;
    #pragma unroll
    for (int k = 0; k < 16; ++k) s += gsum[(size_t)(b*16 + k)*64 + t];
    g[t] = s * (1.f/M_);
    __syncthreads();
    if (t < 32) {
        float a = b1[t];
        for (int f = 0; f < 64; ++f) a += g[f] * w1[f*32 + t];
        hid[t] = fmaxf(a, 0.f);
    }
    __syncthreads();
    if (t == 0) {
        float a = b2[0];
        for (int f = 0; f < 32; ++f) a += hid[f] * w2[f];
        out[b] = a;
    }
}

extern "C" void kernel_launch(void* const* d_in, const int* in_sizes, int n_in,
                              void* d_out, int out_size, void* d_ws, size_t ws_size,
                              hipStream_t stream)
{
    (void)in_sizes; (void)n_in; (void)out_size; (void)ws_size;
    const float* x      = (const float*)d_in[0];
    const float* enc_w1 = (const float*)d_in[2];
    const float* enc_b1 = (const float*)d_in[3];
    const float* enc_w2 = (const float*)d_in[4];
    const float* enc_b2 = (const float*)d_in[5];
    const float* ec1_w1 = (const float*)d_in[6];
    const float* ec1_b1 = (const float*)d_in[7];
    const float* ec1_w2 = (const float*)d_in[8];
    const float* ec1_b2 = (const float*)d_in[9];
    const float* ec2_w1 = (const float*)d_in[10];
    const float* ec2_b1 = (const float*)d_in[11];
    const float* ec2_w2 = (const float*)d_in[12];
    const float* ec2_b2 = (const float*)d_in[13];
    const float* out_w1 = (const float*)d_in[14];
    const float* out_b1 = (const float*)d_in[15];
    const float* out_w2 = (const float*)d_in[16];
    const float* out_b2 = (const float*)d_in[17];

    // ws layout, 34.25 MB total. No f32 h: node features live only as the
    // f16 hi/lo pair (region2); A has its own region1 -> no time-sharing.
    char* ws = (char*)d_ws;
    float*          A   = (float*)(ws);                                  // 16 MB
    _Float16*       hhi = (_Float16*)(ws + (size_t)N_*64*4);             //  8 MB
    _Float16*       hlo = (_Float16*)(ws + (size_t)N_*64*4 + (size_t)N_*64*2); // 8 MB
    unsigned short* idx = (unsigned short*)(ws + (size_t)N_*64*4*2);     //  2 MB
    float*          sq  = (float*)(ws + (size_t)N_*64*4*2 + (size_t)N_*16*2); // 256 KB
    float*          gsum = sq;    // [B*16,64] partial sums (sq dead after knn2)

    enc_kernel<<<N_/256, 256, 0, stream>>>(x, enc_w1, enc_b1, enc_w2, enc_b2,
                                           hhi, hlo, sq);
    // layer 1
    knn_kernel <<<B_*8, 256, 0, stream>>>(hhi, hlo, sq, idx);
    gemmA_kernel<<<N_/256, 256, 0, stream>>>(hhi, hlo, ec1_w1, A);
    edge_kernel<<<N_/64, 256, 0, stream>>>(hhi, hlo, A, idx,
                                           ec1_w1, ec1_b1, ec1_w2, ec1_b2,
                                           sq, nullptr);   // in-place h + sq
    // layer 2
    knn_kernel <<<B_*8, 256, 0, stream>>>(hhi, hlo, sq, idx);
    gemmA_kernel<<<N_/256, 256, 0, stream>>>(hhi, hlo, ec2_w1, A);
    edge_kernel<<<N_/64, 256, 0, stream>>>(hhi, hlo, A, idx,
                                           ec2_w1, ec2_b1, ec2_w2, ec2_b2,
                                           nullptr, gsum);  // fused pool partials
    // final: partial sums -> mean -> output MLP
    poolf_kernel<<<B_, 64, 0, stream>>>(gsum, out_w1, out_b1, out_w2, out_b2,
                                        (float*)d_out);
}

// Round 10
// 350.157 us; speedup vs baseline: 1.1738x; 1.0156x over previous
//
#include <hip/hip_runtime.h>
#include <math.h>

#define B_ 64
#define M_ 1024
#define H_ 64
#define N_ (B_*M_)   // 65536

typedef _Float16 half8 __attribute__((ext_vector_type(8)));
typedef float  floatx4 __attribute__((ext_vector_type(4)));

#define MFMA16(a,b,c) __builtin_amdgcn_mfma_f32_16x16x32_f16(a,b,c,0,0,0)
#define MED3(a,b,c)   __builtin_amdgcn_fmed3f(a,b,c)

// ---------------- encoder: h = relu(relu(x@w1+b1)@w2+b2) -> (hhi,hlo,sq) --------
__global__ __launch_bounds__(256) void enc_kernel(
    const float* __restrict__ x,     // [N,4]
    const float* __restrict__ w1,    // [4,32]
    const float* __restrict__ b1,    // [32]
    const float* __restrict__ w2,    // [32,64]
    const float* __restrict__ b2,    // [64]
    _Float16* __restrict__ hhi,      // [N,64]
    _Float16* __restrict__ hlo,      // [N,64]
    float* __restrict__ sq)          // [N]
{
    __shared__ float sw1[4*32];
    __shared__ float sb1[32];
    __shared__ float sw2[32*64];
    __shared__ float sb2[64];
    int t = threadIdx.x;
    for (int i = t; i < 128; i += 256) sw1[i] = w1[i];
    if (t < 32) sb1[t] = b1[t];
    for (int i = t; i < 2048; i += 256) sw2[i] = w2[i];
    if (t < 64) sb2[t] = b2[t];
    __syncthreads();
    int n = blockIdx.x * 256 + t;
    float4 xv = *(const float4*)(x + (size_t)n*4);
    float hid[32];
    #pragma unroll
    for (int o = 0; o < 32; ++o) {
        float a = sb1[o] + xv.x*sw1[0*32+o] + xv.y*sw1[1*32+o]
                        + xv.z*sw1[2*32+o] + xv.w*sw1[3*32+o];
        hid[o] = fmaxf(a, 0.f);
    }
    float sqa = 0.f;
    #pragma unroll 4
    for (int oc = 0; oc < 16; ++oc) {
        float4 acc = make_float4(sb2[oc*4+0], sb2[oc*4+1], sb2[oc*4+2], sb2[oc*4+3]);
        #pragma unroll
        for (int f = 0; f < 32; ++f) {
            float4 w = *(const float4*)(sw2 + f*64 + oc*4);
            float hv = hid[f];
            acc.x += hv*w.x; acc.y += hv*w.y; acc.z += hv*w.z; acc.w += hv*w.w;
        }
        acc.x = fmaxf(acc.x,0.f); acc.y = fmaxf(acc.y,0.f);
        acc.z = fmaxf(acc.z,0.f); acc.w = fmaxf(acc.w,0.f);
        sqa += acc.x*acc.x + acc.y*acc.y + acc.z*acc.z + acc.w*acc.w;
        union { _Float16 f[4]; uint2 u; } Hh, Hl;
        Hh.f[0]=(_Float16)acc.x; Hh.f[1]=(_Float16)acc.y;
        Hh.f[2]=(_Float16)acc.z; Hh.f[3]=(_Float16)acc.w;
        Hl.f[0]=(_Float16)(acc.x-(float)Hh.f[0]); Hl.f[1]=(_Float16)(acc.y-(float)Hh.f[1]);
        Hl.f[2]=(_Float16)(acc.z-(float)Hh.f[2]); Hl.f[3]=(_Float16)(acc.w-(float)Hh.f[3]);
        *(uint2*)(hhi + (size_t)n*64 + oc*4) = Hh.u;
        *(uint2*)(hlo + (size_t)n*64 + oc*4) = Hl.u;
    }
    sq[n] = sqa;
}

// ---------------- kNN v15: v11 main loop + fused A = h @ W1b (prologue) --------
// Block = 128 queries (4 waves x 32 in 2 MFMA B-groups), grid = 512 blocks.
// PROLOGUE (new): stage W1b hi/lo A-operand frags into the tile buffers (dead
// until main loop), compute A rows for this block's 128 queries from the
// already-loaded Q fragments (48 MFMA/wave), stage the 128x64 A-tile through
// the merge buffer (dead until epilogue), write coalesced to global. This
// replaces the standalone gemmA dispatch. Main loop & merge = v11, unchanged.
__global__ __launch_bounds__(256, 2) void knn_kernel(
    const _Float16* __restrict__ hhi,
    const _Float16* __restrict__ hlo,
    const float* __restrict__ sqg,
    const float* __restrict__ w1,        // [128,64]; rows 64..127 = W1b
    float* __restrict__ A,               // [N,64] out
    unsigned short* __restrict__ knn)    // [N,16]
{
    __shared__ __align__(16) _Float16 bufs[4][32*64];   // H0,H1,L0,L1 (16KB); wf alias
    __shared__ __align__(16) float sqS[1024];           // 4KB
    __shared__ float md[128*65];                        // 33.3KB merge buf; mdA alias

    int t = threadIdx.x, lane = t & 63, w = t >> 6;
    int bi = blockIdx.x;
    int g   = (bi & 7) | ((bi >> 6) << 3);  // 8 blocks/graph share bi%8 -> same XCD L2
    int qt8 = (bi >> 3) & 7;                // which 128-query slice of the graph
    const _Float16* hhig = hhi + (size_t)g*M_*64;
    const _Float16* hlog = hlo + (size_t)g*M_*64;
    const float*    sqb  = sqg + (size_t)g*M_;

    ((float4*)sqS)[t] = ((const float4*)sqb)[t];        // stage sq: 256 x 16B

    // stage W1b A-operand frags (hi/lo) into bufs area (16KB, dead until loop)
    _Float16* wf = &bufs[0][0];
    for (int u = t; u < 512; u += 256) {
        int ulane = u & 63, nt = u >> 7, ks = (u >> 6) & 1;
        int n = nt*16 + (ulane & 15);
        int kbase = ks*32 + ((ulane >> 4) * 8);
        int fh = (((nt*2+ks)*2+0)*64 + ulane)*8;
        int fl = (((nt*2+ks)*2+1)*64 + ulane)*8;
        #pragma unroll
        for (int j = 0; j < 8; ++j) {
            int k = kbase + j;
            float v = w1[4096 + k*64 + n];
            _Float16 hi = (_Float16)v;
            wf[fh+j] = hi;
            wf[fl+j] = (_Float16)(v - (float)hi);
        }
    }

    int m16 = lane & 15, gid = lane >> 4;
    int crow = gid*4, koct = gid*8;
    int sw = m16 & 7;

    // staging role: waves 0,1 -> hi tile, waves 2,3 -> lo tile (32 rows each)
    int u  = ((w & 1) << 6) | lane;         // 0..127 within role pair
    int rr = u >> 3;                        // row 0..15 (subtile 0; +16 for subtile 1)
    int gl = u & 7;                         // logical 16B granule (linear global read)
    int pp = gl ^ (rr & 7);                 // physical granule (XOR swizzle on write)
    const _Float16* srcb = (w < 2 ? hhig : hlog) + rr*64 + gl*8;
    _Float16* dst0 = (w < 2 ? bufs[0] : bufs[2]) + rr*64 + pp*8;
    _Float16* dst1 = (w < 2 ? bufs[1] : bufs[3]) + rr*64 + pp*8;

    // query fragments (B operand): 2 groups of 16 rows
    int qbase = qt8*128 + w*32;
    half8 Q0h0, Q0h1, Q0l0, Q0l1, Q1h0, Q1h1, Q1l0, Q1l1;
    {
        const _Float16* ph = hhig + (size_t)(qbase + m16)*64;
        const _Float16* pl = hlog + (size_t)(qbase + m16)*64;
        Q0h0 = *(const half8*)(ph + koct);
        Q0h1 = *(const half8*)(ph + 32 + koct);
        Q0l0 = *(const half8*)(pl + koct);
        Q0l1 = *(const half8*)(pl + 32 + koct);
        ph += 16*64; pl += 16*64;
        Q1h0 = *(const half8*)(ph + koct);
        Q1h1 = *(const half8*)(ph + 32 + koct);
        Q1l0 = *(const half8*)(pl + koct);
        Q1l1 = *(const half8*)(pl + 32 + koct);
    }

    __syncthreads();                        // wf + sqS ready

    float c10 = 1.f + sqS[qbase + m16];
    float c11 = 1.f + sqS[qbase + 16 + m16];

    // ---- fused gemmA: D[o][q] = sum_k W1b[k][o] h[q][k] via mfma(W,Q) ----
    // acc[r]: row o = nt*16 + crow + r, col q = (qgroup base) + m16.
    float* mdA = md;                        // [128][64] f32 A-tile scratch (32KB)
    #pragma unroll
    for (int nt = 0; nt < 4; ++nt) {
        floatx4 aA = {0.f,0.f,0.f,0.f}, aB = {0.f,0.f,0.f,0.f};
        #pragma unroll
        for (int ks = 0; ks < 2; ++ks) {
            half8 wh = *(const half8*)&wf[(((nt*2+ks)*2+0)*64+lane)*8];
            half8 wl = *(const half8*)&wf[(((nt*2+ks)*2+1)*64+lane)*8];
            half8 qh0 = ks ? Q0h1 : Q0h0, ql0 = ks ? Q0l1 : Q0l0;
            half8 qh1 = ks ? Q1h1 : Q1h0, ql1 = ks ? Q1l1 : Q1l0;
            aA = MFMA16(wh, qh0, aA);
            aA = MFMA16(wh, ql0, aA);
            aA = MFMA16(wl, qh0, aA);
            aB = MFMA16(wh, qh1, aB);
            aB = MFMA16(wh, ql1, aB);
            aB = MFMA16(wl, qh1, aB);
        }
        #pragma unroll
        for (int r = 0; r < 4; ++r) {
            mdA[(w*32 +      m16)*64 + nt*16 + crow + r] = aA[r];
            mdA[(w*32 + 16 + m16)*64 + nt*16 + crow + r] = aB[r];
        }
    }
    __syncthreads();                        // mdA complete; wf reads done

    // coalesced copy: mdA (32KB) -> A rows of this block's 128 queries;
    // simultaneously safe to begin tile staging into bufs (wf dead).
    {
        float4* Ag = (float4*)(A + (size_t)(g*M_ + qt8*128)*64);
        const float4* As = (const float4*)mdA;
        #pragma unroll
        for (int i = 0; i < 8; ++i) Ag[t*8 + i] = As[t*8 + i];
    }

    float bd0[16], bd1[16];
    #pragma unroll
    for (int k = 0; k < 16; ++k) { bd0[k] = INFINITY; bd1[k] = INFINITY; }

    int ts0 = qt8*8 + w*2;      // global 16-cand subtile holding qg0's self
    int ts1 = ts0 + 1;          // ... and qg1's self

    // prologue: tile0 regs -> buf0; prefetch tiles 1,2 into regs
    float4 a0, a1, b0, b1;
    a0 = *(const float4*)(srcb);
    a1 = *(const float4*)(srcb + 1024);
    b0 = *(const float4*)(srcb + 2048);
    b1 = *(const float4*)(srcb + 3072);
    *(float4*)dst0 = a0;  *(float4*)(dst0 + 1024) = a1;
    a0 = *(const float4*)(srcb + 2*2048);
    a1 = *(const float4*)(srcb + 2*2048 + 1024);
    __syncthreads();                        // buf0 ready (and A-copy done)

    int o0 = m16*64 + ((gid ^ sw) * 8);     // swizzled frag offsets (ks0)
    int o1 = o0 ^ 32;                       // ks1 granule ^= 4

    auto insert4 = [&](float (&bdr)[16], floatx4 acc, float4 sqv,
                       unsigned cid, bool st, float c1v) {
        #pragma unroll
        for (int r = 0; r < 4; ++r) {
            float s  = fmaf(-2.f, acc[r], (&sqv.x)[r]);   // sq_j - 2 dot
            float t2 = c1v + s;                           // 1 + d^2  (>0)
            unsigned kb = (__float_as_uint(t2) & 0xFFFFFC00u) | (cid + r);
            float fk = __uint_as_float(kb);
            if (st && (crow + r) == m16) fk = INFINITY;   // self
            float nb0 = fminf(bdr[0], fk);
            #pragma unroll
            for (int k = 15; k >= 1; --k) bdr[k] = MED3(fk, bdr[k-1], bdr[k]);
            bdr[0] = nb0;
        }
    };

    auto compute = [&](int T, const _Float16* bh, const _Float16* bl) {
        #pragma unroll
        for (int s = 0; s < 2; ++s) {
            int ob = s*1024;
            half8 Ah0 = *(const half8*)(bh + ob + o0);
            half8 Ah1 = *(const half8*)(bh + ob + o1);
            half8 Al0 = *(const half8*)(bl + ob + o0);
            half8 Al1 = *(const half8*)(bl + ob + o1);
            float4 sqv = *(const float4*)(sqS + T*32 + s*16 + crow);
            unsigned cid = (unsigned)(T*32 + s*16 + crow);
            int ts = T*2 + s;
            floatx4 acc = {0.f, 0.f, 0.f, 0.f};
            acc = MFMA16(Ah0, Q0h0, acc);
            acc = MFMA16(Ah1, Q0h1, acc);
            acc = MFMA16(Ah0, Q0l0, acc);
            acc = MFMA16(Ah1, Q0l1, acc);
            acc = MFMA16(Al0, Q0h0, acc);
            acc = MFMA16(Al1, Q0h1, acc);
            insert4(bd0, acc, sqv, cid, ts == ts0, c10);
            floatx4 acc2 = {0.f, 0.f, 0.f, 0.f};
            acc2 = MFMA16(Ah0, Q1h0, acc2);
            acc2 = MFMA16(Ah1, Q1h1, acc2);
            acc2 = MFMA16(Ah0, Q1l0, acc2);
            acc2 = MFMA16(Ah1, Q1l1, acc2);
            acc2 = MFMA16(Al0, Q1h0, acc2);
            acc2 = MFMA16(Al1, Q1h1, acc2);
            insert4(bd1, acc2, sqv, cid, ts == ts1, c11);
        }
    };

    // main loop: 32 tiles, 2 per iteration; double-buffered LDS, raw barriers
    #pragma unroll 1
    for (int T = 0; T < 32; T += 2) {
        __builtin_amdgcn_s_barrier();                   // all done reading buf1
        *(float4*)dst1 = b0;  *(float4*)(dst1 + 1024) = b1;   // tile T+1 -> buf1
        { size_t o = (size_t)((T+3)&31)*2048;
          b0 = *(const float4*)(srcb + o);
          b1 = *(const float4*)(srcb + o + 1024); }
        asm volatile("s_waitcnt lgkmcnt(0)" ::: "memory");
        __builtin_amdgcn_s_barrier();                   // buf1 visible to all
        __builtin_amdgcn_sched_barrier(0);
        compute(T, bufs[0], bufs[2]);
        __builtin_amdgcn_s_barrier();                   // all done reading buf0
        *(float4*)dst0 = a0;  *(float4*)(dst0 + 1024) = a1;   // tile T+2 -> buf0
        { size_t o = (size_t)((T+4)&31)*2048;
          a0 = *(const float4*)(srcb + o);
          a1 = *(const float4*)(srcb + o + 1024); }
        asm volatile("s_waitcnt lgkmcnt(0)" ::: "memory");
        __builtin_amdgcn_s_barrier();                   // buf0 visible to all
        __builtin_amdgcn_sched_barrier(0);
        compute(T+1, bufs[1], bufs[3]);
    }

    // ---- merge 4 per-query-gid lists (64 keys/query); waves 0,1 extract ----
    __syncthreads();
    int qrow0 = w*32 + m16;
    #pragma unroll
    for (int k = 0; k < 16; ++k) {
        md[qrow0*65 + gid*16 + k]      = bd0[k];
        md[(qrow0+16)*65 + gid*16 + k] = bd1[k];
    }
    __syncthreads();
    if (w < 2) {
        int q = w*64 + lane;                 // query within block [0,128)
        float b2[16];
        #pragma unroll
        for (int k = 0; k < 16; ++k) b2[k] = INFINITY;
        const float* mrow = md + (size_t)q*65;
        #pragma unroll
        for (int c8 = 0; c8 < 8; ++c8) {
            float sv[8];
            #pragma unroll
            for (int j = 0; j < 8; ++j) sv[j] = mrow[c8*8 + j];
            #pragma unroll
            for (int j = 0; j < 8; ++j) {
                float s = sv[j];
                float nb0 = fminf(b2[0], s);
                #pragma unroll
                for (int k = 15; k >= 1; --k) b2[k] = MED3(s, b2[k-1], b2[k]);
                b2[0] = nb0;
            }
        }
        union { unsigned short us[16]; uint4 v4[2]; } o;
        #pragma unroll
        for (int k = 0; k < 16; ++k)
            o.us[k] = (unsigned short)(__float_as_uint(b2[k]) & 1023u);
        size_t gq = (size_t)g*M_ + qt8*128 + q;
        uint4* dst = (uint4*)(knn + gq*16);
        dst[0] = o.v4[0];
        dst[1] = o.v4[1];
    }
}

// ---------------- EdgeConv v5: hi/lo input, in-place hi/lo+sq OR fused pool ----
__global__ __launch_bounds__(256) void edge_kernel(
    _Float16* hhi,                   // [N,64] in/out (own rows only)
    _Float16* hlo,                   // [N,64] in/out
    const float* __restrict__ A,     // [N,64]
    const unsigned short* __restrict__ knn, // [N,16] local idx
    const float* __restrict__ w1,    // [128,64]
    const float* __restrict__ b1,    // [64]
    const float* __restrict__ w2,    // [64,64]
    const float* __restrict__ b2,    // [64]
    float* __restrict__ sqout,       // [N] (layer 1) or unused
    float* __restrict__ gsum)        // [B*16,64] partial sums or nullptr
{
    __shared__ __align__(16) _Float16 wdf[16*64*8];   // Wd B-frags (16 KB) -> part[]
    __shared__ __align__(16) _Float16 w2f[16*64*8];   // W2 B-frags (16 KB) -> Cs after
    float* CsB = (float*)w2f;                          // Cs[4][16][64] alias (16 KB)
    int t = threadIdx.x;
    for (int u = t; u < 512; u += 256) {
        int ulane = u & 63, nt = u >> 7, ks = (u >> 6) & 1;
        int n = nt*16 + (ulane & 15);
        int kbase = ks*32 + ((ulane >> 4) * 8);
        int fh = (((nt*2+ks)*2+0)*64 + ulane)*8;
        int fl = (((nt*2+ks)*2+1)*64 + ulane)*8;
        #pragma unroll
        for (int j = 0; j < 8; ++j) {
            int k = kbase + j;
            float vd = w1[k*64+n] - w1[4096 + k*64+n];
            _Float16 dh = (_Float16)vd;
            wdf[fh+j] = dh;
            wdf[fl+j] = (_Float16)(vd - (float)dh);
            float v2 = w2[k*64+n];
            _Float16 h2 = (_Float16)v2;
            w2f[fh+j] = h2;
            w2f[fl+j] = (_Float16)(v2 - (float)h2);
        }
    }
    __syncthreads();
    int lane = t & 63, wid = t >> 6;
    int m16 = lane & 15, gid = lane >> 4;
    int koct = gid*8, crow = gid*4;
    int bi = blockIdx.x;
    int g  = (bi & 7) | ((bi >> 7) << 3);    // XCD swizzle: graph's blocks share an XCD
    int qt = (bi >> 3) & 15;
    int i0 = g*M_ + qt*64 + wid*16;          // first node of this wave
    const float* Ab = A + (size_t)g*M_*H_;

    half8 W2r[4][2][2];
    #pragma unroll
    for (int nt = 0; nt < 4; ++nt)
        #pragma unroll
        for (int ks = 0; ks < 2; ++ks)
            #pragma unroll
            for (int p = 0; p < 2; ++p)
                W2r[nt][ks][p] = *(const half8*)&w2f[(((nt*2+ks)*2+p)*64+lane)*8];

    float b1v[4];
    #pragma unroll
    for (int nt = 0; nt < 4; ++nt) b1v[nt] = b1[nt*16+m16];
    float b2v = b2[gid*16+m16];
    __syncthreads();   // all waves done reading w2f -> safe to overwrite with Cs

    // ---- Phase 1: C tile = h(16 nodes) @ Wd + b1 -> CsB (over w2f) ----
    half8 Hh[2], Hl[2];
    #pragma unroll
    for (int ks = 0; ks < 2; ++ks) {
        Hh[ks] = *(const half8*)(hhi + (size_t)(i0+m16)*64 + ks*32 + koct);
        Hl[ks] = *(const half8*)(hlo + (size_t)(i0+m16)*64 + ks*32 + koct);
    }
    #pragma unroll
    for (int nt = 0; nt < 4; ++nt) {
        floatx4 acc = {b1v[nt], b1v[nt], b1v[nt], b1v[nt]};
        #pragma unroll
        for (int ks = 0; ks < 2; ++ks) {
            half8 wh = *(const half8*)&wdf[(((nt*2+ks)*2+0)*64+lane)*8];
            half8 wl = *(const half8*)&wdf[(((nt*2+ks)*2+1)*64+lane)*8];
            acc = MFMA16(Hh[ks], wh, acc);
            acc = MFMA16(Hh[ks], wl, acc);
            acc = MFMA16(Hl[ks], wh, acc);
        }
        #pragma unroll
        for (int r = 0; r < 4; ++r)
            CsB[((wid*16) + crow + r)*64 + nt*16 + m16] = acc[r];
    }
    __syncthreads();   // wdf dead after Phase 1 -> reusable below

    // ---- Phase 2: per node, msg = relu(C + A_j), out = max_e msg@W2 + b2 ----
    const unsigned short* knb = knn + (size_t)i0*16;
    float ssum = 0.f;
    #pragma unroll 2
    for (int nn = 0; nn < 16; ++nn) {
        int j = knb[nn*16 + m16];
        const float* Ap = Ab + (size_t)j*64;
        half8 Mh[2], Ml[2];
        #pragma unroll
        for (int ks = 0; ks < 2; ++ks) {
            float4 a0 = *(const float4*)(Ap + ks*32 + koct);
            float4 a1 = *(const float4*)(Ap + ks*32 + koct + 4);
            const float* cp = &CsB[(wid*16 + nn)*64 + ks*32 + koct];
            float4 c0 = *(const float4*)cp;
            float4 c1 = *(const float4*)(cp+4);
            float mv[8] = {
                fmaxf(a0.x+c0.x,0.f), fmaxf(a0.y+c0.y,0.f),
                fmaxf(a0.z+c0.z,0.f), fmaxf(a0.w+c0.w,0.f),
                fmaxf(a1.x+c1.x,0.f), fmaxf(a1.y+c1.y,0.f),
                fmaxf(a1.z+c1.z,0.f), fmaxf(a1.w+c1.w,0.f)};
            #pragma unroll
            for (int jj = 0; jj < 8; ++jj) {
                _Float16 hi = (_Float16)mv[jj];
                Mh[ks][jj] = hi;
                Ml[ks][jj] = (_Float16)(mv[jj]-(float)hi);
            }
        }
        floatx4 acc[4];
        #pragma unroll
        for (int nt = 0; nt < 4; ++nt) {
            acc[nt] = (floatx4){0.f,0.f,0.f,0.f};
            #pragma unroll
            for (int ks = 0; ks < 2; ++ks) {
                acc[nt] = MFMA16(Mh[ks], W2r[nt][ks][0], acc[nt]);
                acc[nt] = MFMA16(Mh[ks], W2r[nt][ks][1], acc[nt]);
                acc[nt] = MFMA16(Ml[ks], W2r[nt][ks][0], acc[nt]);
            }
        }
        float om[4];
        #pragma unroll
        for (int nt = 0; nt < 4; ++nt) {
            float mr = fmaxf(fmaxf(acc[nt][0], acc[nt][1]),
                             fmaxf(acc[nt][2], acc[nt][3]));
            mr = fmaxf(mr, __shfl_xor(mr, 16, 64));
            mr = fmaxf(mr, __shfl_xor(mr, 32, 64));
            om[nt] = mr;
        }
        float val = (gid == 0) ? om[0] : (gid == 1) ? om[1]
                  : (gid == 2) ? om[2] : om[3];
        float outv = val + b2v;
        if (gsum) {
            ssum += outv;
        } else {
            // in-place hi/lo split of own row + per-node sq (wave reduce)
            _Float16 hi = (_Float16)outv;
            hhi[(size_t)(i0+nn)*64 + gid*16 + m16] = hi;
            hlo[(size_t)(i0+nn)*64 + gid*16 + m16] = (_Float16)(outv - (float)hi);
            float s2 = outv*outv;
            #pragma unroll
            for (int off = 1; off < 64; off <<= 1) s2 += __shfl_xor(s2, off, 64);
            if (lane == 0) sqout[i0+nn] = s2;
        }
    }

    if (gsum) {   // per-block 64-ch partial sum over its 64 nodes
        float* part = (float*)wdf;               // wdf dead after Phase 1
        part[wid*64 + gid*16 + m16] = ssum;
        __syncthreads();
        if (t < 64) {
            float tot = part[t] + part[64+t] + part[128+t] + part[192+t];
            gsum[(size_t)(g*16 + qt)*64 + t] = tot;
        }
    }
}

// ---------------- final pool: partial sums -> mean -> output MLP ----------------
__global__ __launch_bounds__(64) void poolf_kernel(
    const float* __restrict__ gsum, // [B*16,64]
    const float* __restrict__ w1,   // [64,32]
    const float* __restrict__ b1,   // [32]
    const float* __restrict__ w2,   // [32,1]
    const float* __restrict__ b2,   // [1]
    float* __restrict__ out)        // [B]
{
    __shared__ float g[64];
    __shared__ float hid[32];
    int t = threadIdx.x;
    int b = blockIdx.x;
    float s = 0.f;
    #pragma unroll
    for (int k = 0; k < 16; ++k) s += gsum[(size_t)(b*16 + k)*64 + t];
    g[t] = s * (1.f/M_);
    __syncthreads();
    if (t < 32) {
        float a = b1[t];
        for (int f = 0; f < 64; ++f) a += g[f] * w1[f*32 + t];
        hid[t] = fmaxf(a, 0.f);
    }
    __syncthreads();
    if (t == 0) {
        float a = b2[0];
        for (int f = 0; f < 32; ++f) a += hid[f] * w2[f];
        out[b] = a;
    }
}

extern "C" void kernel_launch(void* const* d_in, const int* in_sizes, int n_in,
                              void* d_out, int out_size, void* d_ws, size_t ws_size,
                              hipStream_t stream)
{
    (void)in_sizes; (void)n_in; (void)out_size; (void)ws_size;
    const float* x      = (const float*)d_in[0];
    const float* enc_w1 = (const float*)d_in[2];
    const float* enc_b1 = (const float*)d_in[3];
    const float* enc_w2 = (const float*)d_in[4];
    const float* enc_b2 = (const float*)d_in[5];
    const float* ec1_w1 = (const float*)d_in[6];
    const float* ec1_b1 = (const float*)d_in[7];
    const float* ec1_w2 = (const float*)d_in[8];
    const float* ec1_b2 = (const float*)d_in[9];
    const float* ec2_w1 = (const float*)d_in[10];
    const float* ec2_b1 = (const float*)d_in[11];
    const float* ec2_w2 = (const float*)d_in[12];
    const float* ec2_b2 = (const float*)d_in[13];
    const float* out_w1 = (const float*)d_in[14];
    const float* out_b1 = (const float*)d_in[15];
    const float* out_w2 = (const float*)d_in[16];
    const float* out_b2 = (const float*)d_in[17];

    // ws layout, 34.25 MB total. Node features live only as the f16 hi/lo
    // pair; A (f32) has its own region -> no time-sharing hazards.
    char* ws = (char*)d_ws;
    float*          A   = (float*)(ws);                                  // 16 MB
    _Float16*       hhi = (_Float16*)(ws + (size_t)N_*64*4);             //  8 MB
    _Float16*       hlo = (_Float16*)(ws + (size_t)N_*64*4 + (size_t)N_*64*2); // 8 MB
    unsigned short* idx = (unsigned short*)(ws + (size_t)N_*64*4*2);     //  2 MB
    float*          sq  = (float*)(ws + (size_t)N_*64*4*2 + (size_t)N_*16*2); // 256 KB
    float*          gsum = sq;    // [B*16,64] partial sums (sq dead after knn2)

    enc_kernel<<<N_/256, 256, 0, stream>>>(x, enc_w1, enc_b1, enc_w2, enc_b2,
                                           hhi, hlo, sq);
    // layer 1: knn + fused A1 = h @ W1b(ec1)
    knn_kernel <<<B_*8, 256, 0, stream>>>(hhi, hlo, sq, ec1_w1, A, idx);
    edge_kernel<<<N_/64, 256, 0, stream>>>(hhi, hlo, A, idx,
                                           ec1_w1, ec1_b1, ec1_w2, ec1_b2,
                                           sq, nullptr);   // in-place h + sq
    // layer 2: knn + fused A2 = h @ W1b(ec2)
    knn_kernel <<<B_*8, 256, 0, stream>>>(hhi, hlo, sq, ec2_w1, A, idx);
    edge_kernel<<<N_/64, 256, 0, stream>>>(hhi, hlo, A, idx,
                                           ec2_w1, ec2_b1, ec2_w2, ec2_b2,
                                           nullptr, gsum);  // fused pool partials
    // final: partial sums -> mean -> output MLP
    poolf_kernel<<<B_, 64, 0, stream>>>(gsum, out_w1, out_b1, out_w2, out_b2,
                                        (float*)d_out);
}

// Round 11
// 344.010 us; speedup vs baseline: 1.1947x; 1.0179x over previous
//
#include <hip/hip_runtime.h>
#include <math.h>

#define B_ 64
#define M_ 1024
#define H_ 64
#define N_ (B_*M_)   // 65536

typedef _Float16 half8 __attribute__((ext_vector_type(8)));
typedef float  floatx4 __attribute__((ext_vector_type(4)));

#define MFMA16(a,b,c) __builtin_amdgcn_mfma_f32_16x16x32_f16(a,b,c,0,0,0)
#define MED3(a,b,c)   __builtin_amdgcn_fmed3f(a,b,c)

// ---------------- encoder: h = relu(relu(x@w1+b1)@w2+b2) -> (hhi,hlo,sq) --------
__global__ __launch_bounds__(256) void enc_kernel(
    const float* __restrict__ x,     // [N,4]
    const float* __restrict__ w1,    // [4,32]
    const float* __restrict__ b1,    // [32]
    const float* __restrict__ w2,    // [32,64]
    const float* __restrict__ b2,    // [64]
    _Float16* __restrict__ hhi,      // [N,64]
    _Float16* __restrict__ hlo,      // [N,64]
    float* __restrict__ sq)          // [N]
{
    __shared__ float sw1[4*32];
    __shared__ float sb1[32];
    __shared__ float sw2[32*64];
    __shared__ float sb2[64];
    int t = threadIdx.x;
    for (int i = t; i < 128; i += 256) sw1[i] = w1[i];
    if (t < 32) sb1[t] = b1[t];
    for (int i = t; i < 2048; i += 256) sw2[i] = w2[i];
    if (t < 64) sb2[t] = b2[t];
    __syncthreads();
    int n = blockIdx.x * 256 + t;
    float4 xv = *(const float4*)(x + (size_t)n*4);
    float hid[32];
    #pragma unroll
    for (int o = 0; o < 32; ++o) {
        float a = sb1[o] + xv.x*sw1[0*32+o] + xv.y*sw1[1*32+o]
                        + xv.z*sw1[2*32+o] + xv.w*sw1[3*32+o];
        hid[o] = fmaxf(a, 0.f);
    }
    float sqa = 0.f;
    #pragma unroll 4
    for (int oc = 0; oc < 16; ++oc) {
        float4 acc = make_float4(sb2[oc*4+0], sb2[oc*4+1], sb2[oc*4+2], sb2[oc*4+3]);
        #pragma unroll
        for (int f = 0; f < 32; ++f) {
            float4 w = *(const float4*)(sw2 + f*64 + oc*4);
            float hv = hid[f];
            acc.x += hv*w.x; acc.y += hv*w.y; acc.z += hv*w.z; acc.w += hv*w.w;
        }
        acc.x = fmaxf(acc.x,0.f); acc.y = fmaxf(acc.y,0.f);
        acc.z = fmaxf(acc.z,0.f); acc.w = fmaxf(acc.w,0.f);
        sqa += acc.x*acc.x + acc.y*acc.y + acc.z*acc.z + acc.w*acc.w;
        union { _Float16 f[4]; uint2 u; } Hh, Hl;
        Hh.f[0]=(_Float16)acc.x; Hh.f[1]=(_Float16)acc.y;
        Hh.f[2]=(_Float16)acc.z; Hh.f[3]=(_Float16)acc.w;
        Hl.f[0]=(_Float16)(acc.x-(float)Hh.f[0]); Hl.f[1]=(_Float16)(acc.y-(float)Hh.f[1]);
        Hl.f[2]=(_Float16)(acc.z-(float)Hh.f[2]); Hl.f[3]=(_Float16)(acc.w-(float)Hh.f[3]);
        *(uint2*)(hhi + (size_t)n*64 + oc*4) = Hh.u;
        *(uint2*)(hlo + (size_t)n*64 + oc*4) = Hl.u;
    }
    sq[n] = sqa;
}

// ---------------- kNN v16: v15 + conflict-free mdA swizzle + early prefetch ----
// Block = 128 queries (4 waves x 32 in 2 MFMA B-groups), grid = 512 blocks.
// Fused A = h @ W1b prologue (replaces gemmA dispatch): W1b frags staged in the
// tile buffers, 48 MFMA/wave, A-tile staged through md with an XOR-swizzled
// float4 layout (write: granule (nt*4+gid)^(m16&15); read: lane-major with
// matching unswizzle) -- both sides at the 8-lane/bank-quad floor, zero
// conflicts. Candidate tile-0/1/2 global loads are issued BEFORE the gemmA
// section so HBM latency hides under it. Main loop & merge = v11, unchanged.
__global__ __launch_bounds__(256, 2) void knn_kernel(
    const _Float16* __restrict__ hhi,
    const _Float16* __restrict__ hlo,
    const float* __restrict__ sqg,
    const float* __restrict__ w1,        // [128,64]; rows 64..127 = W1b
    float* __restrict__ A,               // [N,64] out
    unsigned short* __restrict__ knn)    // [N,16]
{
    __shared__ __align__(16) _Float16 bufs[4][32*64];   // H0,H1,L0,L1 (16KB); wf alias
    __shared__ __align__(16) float sqS[1024];           // 4KB
    __shared__ float md[128*65];                        // 33.3KB merge buf; mdA alias

    int t = threadIdx.x, lane = t & 63, w = t >> 6;
    int bi = blockIdx.x;
    int g   = (bi & 7) | ((bi >> 6) << 3);  // 8 blocks/graph share bi%8 -> same XCD L2
    int qt8 = (bi >> 3) & 7;                // which 128-query slice of the graph
    const _Float16* hhig = hhi + (size_t)g*M_*64;
    const _Float16* hlog = hlo + (size_t)g*M_*64;
    const float*    sqb  = sqg + (size_t)g*M_;

    ((float4*)sqS)[t] = ((const float4*)sqb)[t];        // stage sq: 256 x 16B

    int m16 = lane & 15, gid = lane >> 4;
    int crow = gid*4, koct = gid*8;
    int sw = m16 & 7;

    // staging role: waves 0,1 -> hi tile, waves 2,3 -> lo tile (32 rows each)
    int u  = ((w & 1) << 6) | lane;         // 0..127 within role pair
    int rr = u >> 3;                        // row 0..15 (subtile 0; +16 for subtile 1)
    int gl = u & 7;                         // logical 16B granule (linear global read)
    int pp = gl ^ (rr & 7);                 // physical granule (XOR swizzle on write)
    const _Float16* srcb = (w < 2 ? hhig : hlog) + rr*64 + gl*8;
    _Float16* dst0 = (w < 2 ? bufs[0] : bufs[2]) + rr*64 + pp*8;
    _Float16* dst1 = (w < 2 ? bufs[1] : bufs[3]) + rr*64 + pp*8;

    // EARLY: issue candidate tile 0/1/2 global loads (latency hides under gemmA)
    float4 a0, a1, b0, b1;
    a0 = *(const float4*)(srcb);
    a1 = *(const float4*)(srcb + 1024);
    b0 = *(const float4*)(srcb + 2048);
    b1 = *(const float4*)(srcb + 3072);

    // stage W1b A-operand frags (hi/lo) into bufs area (16KB, dead until loop)
    _Float16* wf = &bufs[0][0];
    for (int uu = t; uu < 512; uu += 256) {
        int ulane = uu & 63, nt = uu >> 7, ks = (uu >> 6) & 1;
        int n = nt*16 + (ulane & 15);
        int kbase = ks*32 + ((ulane >> 4) * 8);
        int fh = (((nt*2+ks)*2+0)*64 + ulane)*8;
        int fl = (((nt*2+ks)*2+1)*64 + ulane)*8;
        #pragma unroll
        for (int j = 0; j < 8; ++j) {
            int k = kbase + j;
            float v = w1[4096 + k*64 + n];
            _Float16 hi = (_Float16)v;
            wf[fh+j] = hi;
            wf[fl+j] = (_Float16)(v - (float)hi);
        }
    }

    // query fragments (B operand): 2 groups of 16 rows
    int qbase = qt8*128 + w*32;
    half8 Q0h0, Q0h1, Q0l0, Q0l1, Q1h0, Q1h1, Q1l0, Q1l1;
    {
        const _Float16* ph = hhig + (size_t)(qbase + m16)*64;
        const _Float16* pl = hlog + (size_t)(qbase + m16)*64;
        Q0h0 = *(const half8*)(ph + koct);
        Q0h1 = *(const half8*)(ph + 32 + koct);
        Q0l0 = *(const half8*)(pl + koct);
        Q0l1 = *(const half8*)(pl + 32 + koct);
        ph += 16*64; pl += 16*64;
        Q1h0 = *(const half8*)(ph + koct);
        Q1h1 = *(const half8*)(ph + 32 + koct);
        Q1l0 = *(const half8*)(pl + koct);
        Q1l1 = *(const half8*)(pl + 32 + koct);
    }

    __syncthreads();                        // wf + sqS ready

    float c10 = 1.f + sqS[qbase + m16];
    float c11 = 1.f + sqS[qbase + 16 + m16];

    // ---- fused gemmA: D[o][q] = sum_k W1b[k][o] h[q][k] via mfma(W,Q) ----
    // Lane holds cols o = nt*16+crow..+3 of query q = (group base)+m16.
    // Store as ONE float4 per (nt, group) at XOR-swizzled granule -> no
    // bank conflicts (8 lanes per bank-quad = b128 floor).
    float4* mdA4 = (float4*)md;             // [128 rows][16 float4 granules]
    #pragma unroll
    for (int nt = 0; nt < 4; ++nt) {
        floatx4 aA = {0.f,0.f,0.f,0.f}, aB = {0.f,0.f,0.f,0.f};
        #pragma unroll
        for (int ks = 0; ks < 2; ++ks) {
            half8 wh = *(const half8*)&wf[(((nt*2+ks)*2+0)*64+lane)*8];
            half8 wl = *(const half8*)&wf[(((nt*2+ks)*2+1)*64+lane)*8];
            half8 qh0 = ks ? Q0h1 : Q0h0, ql0 = ks ? Q0l1 : Q0l0;
            half8 qh1 = ks ? Q1h1 : Q1h0, ql1 = ks ? Q1l1 : Q1l0;
            aA = MFMA16(wh, qh0, aA);
            aA = MFMA16(wh, ql0, aA);
            aA = MFMA16(wl, qh0, aA);
            aB = MFMA16(wh, qh1, aB);
            aB = MFMA16(wh, ql1, aB);
            aB = MFMA16(wl, qh1, aB);
        }
        int gsw = (nt*4 + gid) ^ m16;       // swizzled granule (4 bits)
        mdA4[(w*32 +      m16)*16 + gsw] = make_float4(aA[0],aA[1],aA[2],aA[3]);
        mdA4[(w*32 + 16 + m16)*16 + gsw] = make_float4(aB[0],aB[1],aB[2],aB[3]);
    }
    __syncthreads();                        // mdA complete; wf reads done

    // conflict-free, coalesced copy-out: lane-major j = i*256 + t;
    // row = j>>4, granule = (j&15) ^ (row&15)  (unswizzle).
    {
        float4* Ag = (float4*)(A + (size_t)(g*M_ + qt8*128)*64);
        #pragma unroll
        for (int i = 0; i < 8; ++i) {
            int j = i*256 + t;
            int row = j >> 4;
            Ag[j] = mdA4[row*16 + ((j & 15) ^ (row & 15))];
        }
    }

    float bd0[16], bd1[16];
    #pragma unroll
    for (int k = 0; k < 16; ++k) { bd0[k] = INFINITY; bd1[k] = INFINITY; }

    int ts0 = qt8*8 + w*2;      // global 16-cand subtile holding qg0's self
    int ts1 = ts0 + 1;          // ... and qg1's self

    // prologue: tile0 regs -> buf0; prefetch tile 2 into regs
    *(float4*)dst0 = a0;  *(float4*)(dst0 + 1024) = a1;
    a0 = *(const float4*)(srcb + 2*2048);
    a1 = *(const float4*)(srcb + 2*2048 + 1024);
    __syncthreads();                        // buf0 ready (and A-copy done)

    int o0 = m16*64 + ((gid ^ sw) * 8);     // swizzled frag offsets (ks0)
    int o1 = o0 ^ 32;                       // ks1 granule ^= 4

    auto insert4 = [&](float (&bdr)[16], floatx4 acc, float4 sqv,
                       unsigned cid, bool st, float c1v) {
        #pragma unroll
        for (int r = 0; r < 4; ++r) {
            float s  = fmaf(-2.f, acc[r], (&sqv.x)[r]);   // sq_j - 2 dot
            float t2 = c1v + s;                           // 1 + d^2  (>0)
            unsigned kb = (__float_as_uint(t2) & 0xFFFFFC00u) | (cid + r);
            float fk = __uint_as_float(kb);
            if (st && (crow + r) == m16) fk = INFINITY;   // self
            float nb0 = fminf(bdr[0], fk);
            #pragma unroll
            for (int k = 15; k >= 1; --k) bdr[k] = MED3(fk, bdr[k-1], bdr[k]);
            bdr[0] = nb0;
        }
    };

    auto compute = [&](int T, const _Float16* bh, const _Float16* bl) {
        #pragma unroll
        for (int s = 0; s < 2; ++s) {
            int ob = s*1024;
            half8 Ah0 = *(const half8*)(bh + ob + o0);
            half8 Ah1 = *(const half8*)(bh + ob + o1);
            half8 Al0 = *(const half8*)(bl + ob + o0);
            half8 Al1 = *(const half8*)(bl + ob + o1);
            float4 sqv = *(const float4*)(sqS + T*32 + s*16 + crow);
            unsigned cid = (unsigned)(T*32 + s*16 + crow);
            int ts = T*2 + s;
            floatx4 acc = {0.f, 0.f, 0.f, 0.f};
            acc = MFMA16(Ah0, Q0h0, acc);
            acc = MFMA16(Ah1, Q0h1, acc);
            acc = MFMA16(Ah0, Q0l0, acc);
            acc = MFMA16(Ah1, Q0l1, acc);
            acc = MFMA16(Al0, Q0h0, acc);
            acc = MFMA16(Al1, Q0h1, acc);
            insert4(bd0, acc, sqv, cid, ts == ts0, c10);
            floatx4 acc2 = {0.f, 0.f, 0.f, 0.f};
            acc2 = MFMA16(Ah0, Q1h0, acc2);
            acc2 = MFMA16(Ah1, Q1h1, acc2);
            acc2 = MFMA16(Ah0, Q1l0, acc2);
            acc2 = MFMA16(Ah1, Q1l1, acc2);
            acc2 = MFMA16(Al0, Q1h0, acc2);
            acc2 = MFMA16(Al1, Q1h1, acc2);
            insert4(bd1, acc2, sqv, cid, ts == ts1, c11);
        }
    };

    // main loop: 32 tiles, 2 per iteration; double-buffered LDS, raw barriers
    #pragma unroll 1
    for (int T = 0; T < 32; T += 2) {
        __builtin_amdgcn_s_barrier();                   // all done reading buf1
        *(float4*)dst1 = b0;  *(float4*)(dst1 + 1024) = b1;   // tile T+1 -> buf1
        { size_t o = (size_t)((T+3)&31)*2048;
          b0 = *(const float4*)(srcb + o);
          b1 = *(const float4*)(srcb + o + 1024); }
        asm volatile("s_waitcnt lgkmcnt(0)" ::: "memory");
        __builtin_amdgcn_s_barrier();                   // buf1 visible to all
        __builtin_amdgcn_sched_barrier(0);
        compute(T, bufs[0], bufs[2]);
        __builtin_amdgcn_s_barrier();                   // all done reading buf0
        *(float4*)dst0 = a0;  *(float4*)(dst0 + 1024) = a1;   // tile T+2 -> buf0
        { size_t o = (size_t)((T+4)&31)*2048;
          a0 = *(const float4*)(srcb + o);
          a1 = *(const float4*)(srcb + o + 1024); }
        asm volatile("s_waitcnt lgkmcnt(0)" ::: "memory");
        __builtin_amdgcn_s_barrier();                   // buf0 visible to all
        __builtin_amdgcn_sched_barrier(0);
        compute(T+1, bufs[1], bufs[3]);
    }

    // ---- merge 4 per-query-gid lists (64 keys/query); waves 0,1 extract ----
    __syncthreads();
    int qrow0 = w*32 + m16;
    #pragma unroll
    for (int k = 0; k < 16; ++k) {
        md[qrow0*65 + gid*16 + k]      = bd0[k];
        md[(qrow0+16)*65 + gid*16 + k] = bd1[k];
    }
    __syncthreads();
    if (w < 2) {
        int q = w*64 + lane;                 // query within block [0,128)
        float b2[16];
        #pragma unroll
        for (int k = 0; k < 16; ++k) b2[k] = INFINITY;
        const float* mrow = md + (size_t)q*65;
        #pragma unroll
        for (int c8 = 0; c8 < 8; ++c8) {
            float sv[8];
            #pragma unroll
            for (int j = 0; j < 8; ++j) sv[j] = mrow[c8*8 + j];
            #pragma unroll
            for (int j = 0; j < 8; ++j) {
                float s = sv[j];
                float nb0 = fminf(b2[0], s);
                #pragma unroll
                for (int k = 15; k >= 1; --k) b2[k] = MED3(s, b2[k-1], b2[k]);
                b2[0] = nb0;
            }
        }
        union { unsigned short us[16]; uint4 v4[2]; } o;
        #pragma unroll
        for (int k = 0; k < 16; ++k)
            o.us[k] = (unsigned short)(__float_as_uint(b2[k]) & 1023u);
        size_t gq = (size_t)g*M_ + qt8*128 + q;
        uint4* dst = (uint4*)(knn + gq*16);
        dst[0] = o.v4[0];
        dst[1] = o.v4[1];
    }
}

// ---------------- EdgeConv v5: hi/lo input, in-place hi/lo+sq OR fused pool ----
__global__ __launch_bounds__(256) void edge_kernel(
    _Float16* hhi,                   // [N,64] in/out (own rows only)
    _Float16* hlo,                   // [N,64] in/out
    const float* __restrict__ A,     // [N,64]
    const unsigned short* __restrict__ knn, // [N,16] local idx
    const float* __restrict__ w1,    // [128,64]
    const float* __restrict__ b1,    // [64]
    const float* __restrict__ w2,    // [64,64]
    const float* __restrict__ b2,    // [64]
    float* __restrict__ sqout,       // [N] (layer 1) or unused
    float* __restrict__ gsum)        // [B*16,64] partial sums or nullptr
{
    __shared__ __align__(16) _Float16 wdf[16*64*8];   // Wd B-frags (16 KB) -> part[]
    __shared__ __align__(16) _Float16 w2f[16*64*8];   // W2 B-frags (16 KB) -> Cs after
    float* CsB = (float*)w2f;                          // Cs[4][16][64] alias (16 KB)
    int t = threadIdx.x;
    for (int u = t; u < 512; u += 256) {
        int ulane = u & 63, nt = u >> 7, ks = (u >> 6) & 1;
        int n = nt*16 + (ulane & 15);
        int kbase = ks*32 + ((ulane >> 4) * 8);
        int fh = (((nt*2+ks)*2+0)*64 + ulane)*8;
        int fl = (((nt*2+ks)*2+1)*64 + ulane)*8;
        #pragma unroll
        for (int j = 0; j < 8; ++j) {
            int k = kbase + j;
            float vd = w1[k*64+n] - w1[4096 + k*64+n];
            _Float16 dh = (_Float16)vd;
            wdf[fh+j] = dh;
            wdf[fl+j] = (_Float16)(vd - (float)dh);
            float v2 = w2[k*64+n];
            _Float16 h2 = (_Float16)v2;
            w2f[fh+j] = h2;
            w2f[fl+j] = (_Float16)(v2 - (float)h2);
        }
    }
    __syncthreads();
    int lane = t & 63, wid = t >> 6;
    int m16 = lane & 15, gid = lane >> 4;
    int koct = gid*8, crow = gid*4;
    int bi = blockIdx.x;
    int g  = (bi & 7) | ((bi >> 7) << 3);    // XCD swizzle: graph's blocks share an XCD
    int qt = (bi >> 3) & 15;
    int i0 = g*M_ + qt*64 + wid*16;          // first node of this wave
    const float* Ab = A + (size_t)g*M_*H_;

    half8 W2r[4][2][2];
    #pragma unroll
    for (int nt = 0; nt < 4; ++nt)
        #pragma unroll
        for (int ks = 0; ks < 2; ++ks)
            #pragma unroll
            for (int p = 0; p < 2; ++p)
                W2r[nt][ks][p] = *(const half8*)&w2f[(((nt*2+ks)*2+p)*64+lane)*8];

    float b1v[4];
    #pragma unroll
    for (int nt = 0; nt < 4; ++nt) b1v[nt] = b1[nt*16+m16];
    float b2v = b2[gid*16+m16];
    __syncthreads();   // all waves done reading w2f -> safe to overwrite with Cs

    // ---- Phase 1: C tile = h(16 nodes) @ Wd + b1 -> CsB (over w2f) ----
    half8 Hh[2], Hl[2];
    #pragma unroll
    for (int ks = 0; ks < 2; ++ks) {
        Hh[ks] = *(const half8*)(hhi + (size_t)(i0+m16)*64 + ks*32 + koct);
        Hl[ks] = *(const half8*)(hlo + (size_t)(i0+m16)*64 + ks*32 + koct);
    }
    #pragma unroll
    for (int nt = 0; nt < 4; ++nt) {
        floatx4 acc = {b1v[nt], b1v[nt], b1v[nt], b1v[nt]};
        #pragma unroll
        for (int ks = 0; ks < 2; ++ks) {
            half8 wh = *(const half8*)&wdf[(((nt*2+ks)*2+0)*64+lane)*8];
            half8 wl = *(const half8*)&wdf[(((nt*2+ks)*2+1)*64+lane)*8];
            acc = MFMA16(Hh[ks], wh, acc);
            acc = MFMA16(Hh[ks], wl, acc);
            acc = MFMA16(Hl[ks], wh, acc);
        }
        #pragma unroll
        for (int r = 0; r < 4; ++r)
            CsB[((wid*16) + crow + r)*64 + nt*16 + m16] = acc[r];
    }
    __syncthreads();   // wdf dead after Phase 1 -> reusable below

    // ---- Phase 2: per node, msg = relu(C + A_j), out = max_e msg@W2 + b2 ----
    const unsigned short* knb = knn + (size_t)i0*16;
    float ssum = 0.f;
    #pragma unroll 2
    for (int nn = 0; nn < 16; ++nn) {
        int j = knb[nn*16 + m16];
        const float* Ap = Ab + (size_t)j*64;
        half8 Mh[2], Ml[2];
        #pragma unroll
        for (int ks = 0; ks < 2; ++ks) {
            float4 a0 = *(const float4*)(Ap + ks*32 + koct);
            float4 a1 = *(const float4*)(Ap + ks*32 + koct + 4);
            const float* cp = &CsB[(wid*16 + nn)*64 + ks*32 + koct];
            float4 c0 = *(const float4*)cp;
            float4 c1 = *(const float4*)(cp+4);
            float mv[8] = {
                fmaxf(a0.x+c0.x,0.f), fmaxf(a0.y+c0.y,0.f),
                fmaxf(a0.z+c0.z,0.f), fmaxf(a0.w+c0.w,0.f),
                fmaxf(a1.x+c1.x,0.f), fmaxf(a1.y+c1.y,0.f),
                fmaxf(a1.z+c1.z,0.f), fmaxf(a1.w+c1.w,0.f)};
            #pragma unroll
            for (int jj = 0; jj < 8; ++jj) {
                _Float16 hi = (_Float16)mv[jj];
                Mh[ks][jj] = hi;
                Ml[ks][jj] = (_Float16)(mv[jj]-(float)hi);
            }
        }
        floatx4 acc[4];
        #pragma unroll
        for (int nt = 0; nt < 4; ++nt) {
            acc[nt] = (floatx4){0.f,0.f,0.f,0.f};
            #pragma unroll
            for (int ks = 0; ks < 2; ++ks) {
                acc[nt] = MFMA16(Mh[ks], W2r[nt][ks][0], acc[nt]);
                acc[nt] = MFMA16(Mh[ks], W2r[nt][ks][1], acc[nt]);
                acc[nt] = MFMA16(Ml[ks], W2r[nt][ks][0], acc[nt]);
            }
        }
        float om[4];
        #pragma unroll
        for (int nt = 0; nt < 4; ++nt) {
            float mr = fmaxf(fmaxf(acc[nt][0], acc[nt][1]),
                             fmaxf(acc[nt][2], acc[nt][3]));
            mr = fmaxf(mr, __shfl_xor(mr, 16, 64));
            mr = fmaxf(mr, __shfl_xor(mr, 32, 64));
            om[nt] = mr;
        }
        float val = (gid == 0) ? om[0] : (gid == 1) ? om[1]
                  : (gid == 2) ? om[2] : om[3];
        float outv = val + b2v;
        if (gsum) {
            ssum += outv;
        } else {
            // in-place hi/lo split of own row + per-node sq (wave reduce)
            _Float16 hi = (_Float16)outv;
            hhi[(size_t)(i0+nn)*64 + gid*16 + m16] = hi;
            hlo[(size_t)(i0+nn)*64 + gid*16 + m16] = (_Float16)(outv - (float)hi);
            float s2 = outv*outv;
            #pragma unroll
            for (int off = 1; off < 64; off <<= 1) s2 += __shfl_xor(s2, off, 64);
            if (lane == 0) sqout[i0+nn] = s2;
        }
    }

    if (gsum) {   // per-block 64-ch partial sum over its 64 nodes
        float* part = (float*)wdf;               // wdf dead after Phase 1
        part[wid*64 + gid*16 + m16] = ssum;
        __syncthreads();
        if (t < 64) {
            float tot = part[t] + part[64+t] + part[128+t] + part[192+t];
            gsum[(size_t)(g*16 + qt)*64 + t] = tot;
        }
    }
}

// ---------------- final pool: partial sums -> mean -> output MLP ----------------
__global__ __launch_bounds__(64) void poolf_kernel(
    const float* __restrict__ gsum, // [B*16,64]
    const float* __restrict__ w1,   // [64,32]
    const float* __restrict__ b1,   // [32]
    const float* __restrict__ w2,   // [32,1]
    const float* __restrict__ b2,   // [1]
    float* __restrict__ out)        // [B]
{
    __shared__ float g[64];
    __shared__ float hid[32];
    int t = threadIdx.x;
    int b = blockIdx.x;
    float s = 0.f;
    #pragma unroll
    for (int k = 0; k < 16; ++k) s += gsum[(size_t)(b*16 + k)*64 + t];
    g[t] = s * (1.f/M_);
    __syncthreads();
    if (t < 32) {
        float a = b1[t];
        for (int f = 0; f < 64; ++f) a += g[f] * w1[f*32 + t];
        hid[t] = fmaxf(a, 0.f);
    }
    __syncthreads();
    if (t == 0) {
        float a = b2[0];
        for (int f = 0; f < 32; ++f) a += hid[f] * w2[f];
        out[b] = a;
    }
}

extern "C" void kernel_launch(void* const* d_in, const int* in_sizes, int n_in,
                              void* d_out, int out_size, void* d_ws, size_t ws_size,
                              hipStream_t stream)
{
    (void)in_sizes; (void)n_in; (void)out_size; (void)ws_size;
    const float* x      = (const float*)d_in[0];
    const float* enc_w1 = (const float*)d_in[2];
    const float* enc_b1 = (const float*)d_in[3];
    const float* enc_w2 = (const float*)d_in[4];
    const float* enc_b2 = (const float*)d_in[5];
    const float* ec1_w1 = (const float*)d_in[6];
    const float* ec1_b1 = (const float*)d_in[7];
    const float* ec1_w2 = (const float*)d_in[8];
    const float* ec1_b2 = (const float*)d_in[9];
    const float* ec2_w1 = (const float*)d_in[10];
    const float* ec2_b1 = (const float*)d_in[11];
    const float* ec2_w2 = (const float*)d_in[12];
    const float* ec2_b2 = (const float*)d_in[13];
    const float* out_w1 = (const float*)d_in[14];
    const float* out_b1 = (const float*)d_in[15];
    const float* out_w2 = (const float*)d_in[16];
    const float* out_b2 = (const float*)d_in[17];

    // ws layout, 34.25 MB total. Node features live only as the f16 hi/lo
    // pair; A (f32) has its own region -> no time-sharing hazards.
    char* ws = (char*)d_ws;
    float*          A   = (float*)(ws);                                  // 16 MB
    _Float16*       hhi = (_Float16*)(ws + (size_t)N_*64*4);             //  8 MB
    _Float16*       hlo = (_Float16*)(ws + (size_t)N_*64*4 + (size_t)N_*64*2); // 8 MB
    unsigned short* idx = (unsigned short*)(ws + (size_t)N_*64*4*2);     //  2 MB
    float*          sq  = (float*)(ws + (size_t)N_*64*4*2 + (size_t)N_*16*2); // 256 KB
    float*          gsum = sq;    // [B*16,64] partial sums (sq dead after knn2)

    enc_kernel<<<N_/256, 256, 0, stream>>>(x, enc_w1, enc_b1, enc_w2, enc_b2,
                                           hhi, hlo, sq);
    // layer 1: knn + fused A1 = h @ W1b(ec1)
    knn_kernel <<<B_*8, 256, 0, stream>>>(hhi, hlo, sq, ec1_w1, A, idx);
    edge_kernel<<<N_/64, 256, 0, stream>>>(hhi, hlo, A, idx,
                                           ec1_w1, ec1_b1, ec1_w2, ec1_b2,
                                           sq, nullptr);   // in-place h + sq
    // layer 2: knn + fused A2 = h @ W1b(ec2)
    knn_kernel <<<B_*8, 256, 0, stream>>>(hhi, hlo, sq, ec2_w1, A, idx);
    edge_kernel<<<N_/64, 256, 0, stream>>>(hhi, hlo, A, idx,
                                           ec2_w1, ec2_b1, ec2_w2, ec2_b2,
                                           nullptr, gsum);  // fused pool partials
    // final: partial sums -> mean -> output MLP
    poolf_kernel<<<B_, 64, 0, stream>>>(gsum, out_w1, out_b1, out_w2, out_b2,
                                        (float*)d_out);
}